// Round 2
// baseline (2754.312 us; speedup 1.0000x reference)
//
#include <hip/hip_runtime.h>

namespace {

constexpr int BATCH = 8;
constexpr int SLEN  = 262144;
constexpr int TT    = 1023;   // (262144-512)/256 + 1
constexpr int NF    = 257;    // rfft bins
constexpr int FP2   = NF + 2; // padded freq row (zeros at [0] and [258])
constexpr int NCH   = 24;     // channels stored in H
constexpr int NBT   = BATCH * TT;       // 8184
constexpr int FRS   = NCH * FP2;        // frame stride in floats (6216)
constexpr float EPS = 1e-5f;

// Bijective XCD swizzle: NBT = 8*1023 exactly; each XCD gets one batch
// element, contiguous in t -> t-1/t-2 frame re-reads are same-XCD L2 hits.
__device__ inline int swz(int bid) { return (bid & 7) * (NBT / 8) + (bid >> 3); }

// ---------------------------------------------------------------------------
// Kernel A: STFT (hann, 512-pt rfft via folded direct DFT) + l0 TD block.
// One workgroup per (b,t). Writes H channels 0..7 (padded rows) + stats0.
// ---------------------------------------------------------------------------
__global__ __launch_bounds__(256, 4) void stft_l0_kernel(
    const float* __restrict__ x,
    const float* __restrict__ W1g, const float* __restrict__ b1g,
    const float* __restrict__ W2g, const float* __restrict__ b2g,
    float* __restrict__ H, float* __restrict__ stats0)
{
  __shared__ float2 cs[512];     // {cos, sin}(2*pi*n/512)
  __shared__ float  xw[512];     // windowed frame
  __shared__ float2 ab[256];     // {xw[n]+xw[512-n], xw[n]-xw[512-n]}
  __shared__ float  sre[FP2];
  __shared__ float  sim[FP2];
  __shared__ float  h1[4][FP2];
  __shared__ float  wW1[24], wb1[4], wW2[96], wb2[8];
  __shared__ float  red[8];

  const int tid = threadIdx.x;
  const int bt  = swz(blockIdx.x);
  const int b   = bt / TT;
  const int t   = bt - b * TT;
  const float* xp = x + (size_t)b * SLEN + (size_t)t * 256;

  if (tid < 24) wW1[tid] = W1g[tid];
  if (tid < 4)  wb1[tid] = b1g[tid];
  if (tid < 96) wW2[tid] = W2g[tid];
  if (tid < 8)  wb2[tid] = b2g[tid];

  const float STEP = 6.283185307179586f / 512.0f;
  for (int n = tid; n < 512; n += 256) {
    float sv, cv;
    sincosf(STEP * (float)n, &sv, &cv);
    cs[n] = make_float2(cv, sv);
    xw[n] = xp[n] * (0.5f - 0.5f * cv);   // hann window
  }
  __syncthreads();

  if (tid >= 1) {  // n = 1..255
    float u = xw[tid], v = xw[512 - tid];
    ab[tid] = make_float2(u + v, u - v);
  }
  __syncthreads();

  const float x0 = xw[0], x256 = xw[256];
  for (int k = tid; k < NF; k += 256) {
    float re = x0 + ((k & 1) ? -x256 : x256);
    float im = 0.f;
    int idx = k;  // (k*n) & 511, starting at n=1
    #pragma unroll 4
    for (int n = 1; n < 256; ++n) {
      float2 w = cs[idx];
      float2 p = ab[n];
      re = fmaf(p.x, w.x, re);
      im = fmaf(-p.y, w.y, im);
      idx = (idx + k) & 511;
    }
    sre[1 + k] = re;
    sim[1 + k] = im;
  }
  if (tid == 0) { sre[0] = 0.f; sim[0] = 0.f; sre[FP2-1] = 0.f; sim[FP2-1] = 0.f; }
  __syncthreads();

  // conv1: (f,2) -> (f,4), k=3 same, relu
  for (int f = tid; f < NF; f += 256) {
    float acc[4] = {wb1[0], wb1[1], wb1[2], wb1[3]};
    #pragma unroll
    for (int i = 0; i < 3; ++i) {
      float vr = sre[f + i], vi = sim[f + i];
      #pragma unroll
      for (int c = 0; c < 4; ++c)
        acc[c] = fmaf(vr, wW1[(i*2+0)*4 + c], fmaf(vi, wW1[(i*2+1)*4 + c], acc[c]));
    }
    #pragma unroll
    for (int c = 0; c < 4; ++c) h1[c][f + 1] = fmaxf(acc[c], 0.f);
  }
  if (tid < 4) { h1[tid][0] = 0.f; h1[tid][FP2-1] = 0.f; }
  __syncthreads();

  // conv2: (f,4) -> (f,8), k=3 same, outer relu, store padded channel-major
  const size_t obase = (size_t)bt * FRS;
  float ps1 = 0.f, ps2 = 0.f;
  for (int f = tid; f < NF; f += 256) {
    float acc[8];
    #pragma unroll
    for (int c = 0; c < 8; ++c) acc[c] = wb2[c];
    #pragma unroll
    for (int i = 0; i < 3; ++i)
      #pragma unroll
      for (int c4 = 0; c4 < 4; ++c4) {
        float hv = h1[c4][f + i];
        #pragma unroll
        for (int c = 0; c < 8; ++c)
          acc[c] = fmaf(hv, wW2[(i*4+c4)*8 + c], acc[c]);
      }
    #pragma unroll
    for (int c = 0; c < 8; ++c) {
      float v = fmaxf(acc[c], 0.f);
      H[obase + (size_t)c * FP2 + 1 + f] = v;
      ps1 += v;
      ps2 = fmaf(v, v, ps2);
    }
  }
  if (tid < 8) {  // zero the row pads
    H[obase + (size_t)tid * FP2] = 0.f;
    H[obase + (size_t)tid * FP2 + FP2 - 1] = 0.f;
  }
  // block-reduce partial LN stats of these 8 channels
  #pragma unroll
  for (int off = 32; off > 0; off >>= 1) {
    ps1 += __shfl_down(ps1, off, 64);
    ps2 += __shfl_down(ps2, off, 64);
  }
  if ((tid & 63) == 0) { red[(tid >> 6) * 2] = ps1; red[(tid >> 6) * 2 + 1] = ps2; }
  __syncthreads();
  if (tid == 0) {
    stats0[bt * 2]     = red[0] + red[2] + red[4] + red[6];
    stats0[bt * 2 + 1] = red[1] + red[3] + red[5] + red[7];
  }
}

// ---------------------------------------------------------------------------
// Transpose LN/depthwise tables to padded channel-major.
// dst layout: [0,NELP) gT, [NELP,2NELP) bnT, [2NELP,5NELP) dwT[dt][c][fp]
// pad positions (fp==0, fp==FP2-1) are 0.
// ---------------------------------------------------------------------------
template<int CIN>
__global__ __launch_bounds__(256) void transpose_tbl(
    const float* __restrict__ g, const float* __restrict__ bn,
    const float* __restrict__ dw, float* __restrict__ dst)
{
  constexpr int NELP = CIN * FP2;
  int idx = blockIdx.x * 256 + threadIdx.x;
  if (idx >= 5 * NELP) return;
  int plane = idx / NELP;
  int r = idx - plane * NELP;
  int c = r / FP2, fp = r - c * FP2;
  float v = 0.f;
  if (fp >= 1 && fp <= NF) {
    int f = fp - 1;
    if (plane == 0)      v = g[f * CIN + c];
    else if (plane == 1) v = bn[f * CIN + c];
    else                 v = dw[(f * CIN + c) * 3 + (plane - 2)];
  }
  dst[idx] = v;
}

// ---------------------------------------------------------------------------
// Layer: LN (stats precomputed by producers) + causal depthwise(K=3) + TD
// block. One workgroup per (b,t), no in-kernel reductions for LN.
// HEAD fuses fc1/fc2/sigmoid.
// ---------------------------------------------------------------------------
template<int CIN, bool HEAD>
__global__ __launch_bounds__(256, 4) void layer_kernel(
    const float* __restrict__ H, float* __restrict__ Hout,
    const float* __restrict__ st0, const float* __restrict__ st1,
    const float* __restrict__ st2, float* __restrict__ stats_out,
    const float* __restrict__ tbl,
    const float* __restrict__ W1g, const float* __restrict__ b1g,
    const float* __restrict__ W2g, const float* __restrict__ b2g,
    const float* __restrict__ fc1W, const float* __restrict__ fc1b,
    const float* __restrict__ fc2W, const float* __restrict__ fc2b,
    float* __restrict__ out)
{
  constexpr int NELP  = CIN * FP2;
  constexpr int NEL   = CIN * NF;      // true LN element count (no pads)
  constexpr int NPERP = (NELP + 255) / 256;

  __shared__ float y[NELP];            // depthwise output (padded rows)
  __shared__ float h1s[8 * FP2];       // conv1 output (padded rows)
  __shared__ float wW1[3 * CIN * 8], wb1[8], wW2[192], wb2[8];
  __shared__ float red[8];
  __shared__ float wfc1[HEAD ? 96 : 1];

  const int tid = threadIdx.x;
  const int bt  = swz(blockIdx.x);
  const int b   = bt / TT;
  const int t   = bt - b * TT;

  const float* gT  = tbl;
  const float* bnT = tbl + NELP;
  const float* dwT = tbl + 2 * NELP;

  // init: weights + h1s row pads (conv1 writes only interior)
  for (int i = tid; i < 3 * CIN * 8; i += 256) wW1[i] = W1g[i];
  if (tid < 192) wW2[tid] = W2g[tid];
  if (tid < 8) {
    wb1[tid] = b1g[tid]; wb2[tid] = b2g[tid];
    h1s[tid * FP2] = 0.f; h1s[tid * FP2 + FP2 - 1] = 0.f;
  }
  if constexpr (HEAD) { if (tid < 96) wfc1[tid] = fc1W[tid]; }

  // per-frame LN stats from producer partials (uniform, cheap)
  float mu[3], rs[3];
  #pragma unroll
  for (int dt = 0; dt < 3; ++dt) {
    const int tt = t - 2 + dt;
    if (tt >= 0) {
      const int fb = b * TT + tt;
      float s1 = st0[fb * 2], s2 = st0[fb * 2 + 1];
      if constexpr (CIN >= 16) { s1 += st1[fb * 2]; s2 += st1[fb * 2 + 1]; }
      if constexpr (CIN >= 24) { s1 += st2[fb * 2]; s2 += st2[fb * 2 + 1]; }
      const float m = s1 * (1.0f / NEL);
      mu[dt] = m;
      rs[dt] = rsqrtf(s2 * (1.0f / NEL) - m * m + EPS);
    } else { mu[dt] = 0.f; rs[dt] = 0.f; }
  }

  // y-fill: normalize 3 frames + causal depthwise, pure register accumulate
  const float* f0 = H + (size_t)(b * TT + t - 2) * FRS;
  const float* f1 = f0 + FRS;
  const float* f2 = f1 + FRS;
  #pragma unroll
  for (int j = 0; j < NPERP; ++j) {
    const int idx = tid + j * 256;
    if (idx < NELP) {
      const float gv = gT[idx], bv = bnT[idx];
      float yv = 0.f;
      if (t >= 2) {
        float xn = fmaf((f0[idx] - mu[0]) * rs[0], gv, bv);
        yv = xn * dwT[idx];
      }
      if (t >= 1) {
        float xn = fmaf((f1[idx] - mu[1]) * rs[1], gv, bv);
        yv = fmaf(xn, dwT[NELP + idx], yv);
      }
      {
        float xn = fmaf((f2[idx] - mu[2]) * rs[2], gv, bv);
        yv = fmaf(xn, dwT[2 * NELP + idx], yv);
      }
      y[idx] = yv;   // pads: g/bn/dw are 0 there -> yv == 0
    }
  }
  __syncthreads();

  // conv1: (f,CIN) -> (f,8), k=3 same, relu
  for (int f = tid; f < NF; f += 256) {
    float acc[8];
    #pragma unroll
    for (int c = 0; c < 8; ++c) acc[c] = wb1[c];
    #pragma unroll
    for (int i = 0; i < 3; ++i)
      for (int cin = 0; cin < CIN; ++cin) {
        float yv = y[cin * FP2 + f + i];
        #pragma unroll
        for (int c = 0; c < 8; ++c)
          acc[c] = fmaf(yv, wW1[(i * CIN + cin) * 8 + c], acc[c]);
      }
    #pragma unroll
    for (int c = 0; c < 8; ++c) h1s[c * FP2 + f + 1] = fmaxf(acc[c], 0.f);
  }
  __syncthreads();

  // conv2: (f,8) -> (f,8), k=3 same, outer relu
  float* out2 = y;  // y is dead after conv1: reuse as out2[c*NF+f] (HEAD)
  float ps1 = 0.f, ps2 = 0.f;
  for (int f = tid; f < NF; f += 256) {
    float acc[8];
    #pragma unroll
    for (int c = 0; c < 8; ++c) acc[c] = wb2[c];
    #pragma unroll
    for (int i = 0; i < 3; ++i)
      #pragma unroll
      for (int c8 = 0; c8 < 8; ++c8) {
        float hv = h1s[c8 * FP2 + f + i];
        #pragma unroll
        for (int c = 0; c < 8; ++c)
          acc[c] = fmaf(hv, wW2[(i * 8 + c8) * 8 + c], acc[c]);
      }
    if constexpr (!HEAD) {
      const size_t obase = (size_t)bt * FRS + (size_t)CIN * FP2;
      #pragma unroll
      for (int c = 0; c < 8; ++c) {
        float v = fmaxf(acc[c], 0.f);
        Hout[obase + (size_t)c * FP2 + 1 + f] = v;
        ps1 += v;
        ps2 = fmaf(v, v, ps2);
      }
    } else {
      #pragma unroll
      for (int c = 0; c < 8; ++c)
        out2[c * NF + f] = fmaxf(acc[c], 0.f);
    }
  }

  if constexpr (!HEAD) {
    if (tid < 8) {  // zero output row pads
      const size_t obase = (size_t)bt * FRS + (size_t)CIN * FP2;
      Hout[obase + (size_t)tid * FP2] = 0.f;
      Hout[obase + (size_t)tid * FP2 + FP2 - 1] = 0.f;
    }
    #pragma unroll
    for (int off = 32; off > 0; off >>= 1) {
      ps1 += __shfl_down(ps1, off, 64);
      ps2 += __shfl_down(ps2, off, 64);
    }
    if ((tid & 63) == 0) { red[(tid >> 6) * 2] = ps1; red[(tid >> 6) * 2 + 1] = ps2; }
    __syncthreads();
    if (tid == 0) {
      stats_out[bt * 2]     = red[0] + red[2] + red[4] + red[6];
      stats_out[bt * 2 + 1] = red[1] + red[3] + red[5] + red[7];
    }
  } else {
    __syncthreads();
    // head: fc1 over [x(24ch) ++ out2(8ch)], VALID k=3, relu, fc2, sigmoid
    const float* xg = H + (size_t)bt * FRS;  // frame t raw input (L2-warm)
    float partial = 0.f;
    if (tid < NF - 2) {
      float acc = fc1b[0];
      #pragma unroll
      for (int i = 0; i < 3; ++i) {
        for (int c = 0; c < 24; ++c)
          acc = fmaf(xg[c * FP2 + 1 + tid + i], wfc1[i * 32 + c], acc);
        #pragma unroll
        for (int c = 0; c < 8; ++c)
          acc = fmaf(out2[c * NF + tid + i], wfc1[i * 32 + 24 + c], acc);
      }
      acc = fmaxf(acc, 0.f);
      partial = acc * fc2W[tid];
    }
    #pragma unroll
    for (int off = 32; off > 0; off >>= 1) partial += __shfl_down(partial, off, 64);
    if ((tid & 63) == 0) red[tid >> 6] = partial;
    __syncthreads();
    if (tid == 0) {
      float tot = red[0] + red[1] + red[2] + red[3] + fc2b[0];
      out[bt] = 1.0f / (1.0f + expf(-tot));
    }
  }
}

}  // namespace

extern "C" void kernel_launch(void* const* d_in, const int* in_sizes, int n_in,
                              void* d_out, int out_size, void* d_ws, size_t ws_size,
                              hipStream_t stream) {
  const float* x = (const float*)d_in[0];
  float* out = (float*)d_out;
  float* ws  = (float*)d_ws;

  // Workspace layout (floats)
  const size_t Hsz = (size_t)NBT * FRS;   // 50,871,744
  float* H    = ws;
  float* st0  = H + Hsz;
  float* st1  = st0 + 2 * NBT;
  float* st2  = st1 + 2 * NBT;
  float* tbl1 = st2 + 2 * NBT;
  float* tbl2 = tbl1 + 5 * (8 * FP2);
  float* tbl3 = tbl2 + 5 * (16 * FP2);

  dim3 blk(256);

  transpose_tbl<8><<<dim3((5 * 8 * FP2 + 255) / 256), blk, 0, stream>>>(
      (const float*)d_in[5], (const float*)d_in[6], (const float*)d_in[7], tbl1);
  transpose_tbl<16><<<dim3((5 * 16 * FP2 + 255) / 256), blk, 0, stream>>>(
      (const float*)d_in[12], (const float*)d_in[13], (const float*)d_in[14], tbl2);
  transpose_tbl<24><<<dim3((5 * 24 * FP2 + 255) / 256), blk, 0, stream>>>(
      (const float*)d_in[19], (const float*)d_in[20], (const float*)d_in[21], tbl3);

  stft_l0_kernel<<<dim3(NBT), blk, 0, stream>>>(
      x, (const float*)d_in[1], (const float*)d_in[2],
      (const float*)d_in[3], (const float*)d_in[4], H, st0);

  layer_kernel<8, false><<<dim3(NBT), blk, 0, stream>>>(
      H, H, st0, nullptr, nullptr, st1, tbl1,
      (const float*)d_in[8], (const float*)d_in[9],
      (const float*)d_in[10], (const float*)d_in[11],
      nullptr, nullptr, nullptr, nullptr, nullptr);

  layer_kernel<16, false><<<dim3(NBT), blk, 0, stream>>>(
      H, H, st0, st1, nullptr, st2, tbl2,
      (const float*)d_in[15], (const float*)d_in[16],
      (const float*)d_in[17], (const float*)d_in[18],
      nullptr, nullptr, nullptr, nullptr, nullptr);

  layer_kernel<24, true><<<dim3(NBT), blk, 0, stream>>>(
      H, nullptr, st0, st1, st2, nullptr, tbl3,
      (const float*)d_in[22], (const float*)d_in[23],
      (const float*)d_in[24], (const float*)d_in[25],
      (const float*)d_in[26], (const float*)d_in[27],
      (const float*)d_in[28], (const float*)d_in[29],
      out);
}

// Round 3
// 2427.666 us; speedup vs baseline: 1.1346x; 1.1346x over previous
//
#include <hip/hip_runtime.h>

namespace {

constexpr int BATCH = 8;
constexpr int SLEN  = 262144;
constexpr int TT    = 1023;   // (262144-512)/256 + 1
constexpr int NF    = 257;    // rfft bins
constexpr int NCH   = 24;     // channels stored in H
constexpr int NBT   = BATCH * TT;   // 8184
constexpr int FRS   = NCH * NF;     // frame stride (6168 floats)
constexpr int TS    = 9;            // frames per strip block
constexpr int SPB   = (TT + TS - 1) / TS;  // 114 strips per batch
constexpr float EPS = 1e-5f;

// ---------------------------------------------------------------------------
// Kernel A: STFT (hann, 512-pt rfft via folded direct DFT) + l0 TD block.
// One workgroup per (b,t). Writes H channels 0..7 + LN partial stats st0.
// ---------------------------------------------------------------------------
__global__ __launch_bounds__(256) void stft_l0_kernel(
    const float* __restrict__ x,
    const float* __restrict__ W1g, const float* __restrict__ b1g,
    const float* __restrict__ W2g, const float* __restrict__ b2g,
    float* __restrict__ H, float* __restrict__ stats0)
{
  __shared__ float2 cs[512];     // {cos, sin}(2*pi*n/512)
  __shared__ float  xw[512];     // windowed frame
  __shared__ float2 ab[256];     // {xw[n]+xw[512-n], xw[n]-xw[512-n]}
  __shared__ float  sre[NF + 2];
  __shared__ float  sim[NF + 2];
  __shared__ float  h1[4][NF + 2];
  __shared__ float  wW1[24], wb1[4], wW2[96], wb2[8];
  __shared__ float  red[8];

  const int tid = threadIdx.x;
  const int bt  = blockIdx.x;
  const int b   = bt / TT;
  const int t   = bt - b * TT;
  const float* xp = x + (size_t)b * SLEN + (size_t)t * 256;

  if (tid < 24) wW1[tid] = W1g[tid];
  if (tid < 4)  wb1[tid] = b1g[tid];
  if (tid < 96) wW2[tid] = W2g[tid];
  if (tid < 8)  wb2[tid] = b2g[tid];

  const float STEP = 6.283185307179586f / 512.0f;
  for (int n = tid; n < 512; n += 256) {
    float sv, cv;
    sincosf(STEP * (float)n, &sv, &cv);
    cs[n] = make_float2(cv, sv);
    xw[n] = xp[n] * (0.5f - 0.5f * cv);   // hann window
  }
  __syncthreads();

  if (tid >= 1) {  // n = 1..255
    float u = xw[tid], v = xw[512 - tid];
    ab[tid] = make_float2(u + v, u - v);
  }
  __syncthreads();

  const float x0 = xw[0], x256 = xw[256];
  for (int k = tid; k < NF; k += 256) {
    float re = x0 + ((k & 1) ? -x256 : x256);
    float im = 0.f;
    int idx = k;  // (k*n) & 511, starting at n=1
    #pragma unroll 4
    for (int n = 1; n < 256; ++n) {
      float2 w = cs[idx];
      float2 p = ab[n];
      re = fmaf(p.x, w.x, re);
      im = fmaf(-p.y, w.y, im);
      idx = (idx + k) & 511;
    }
    sre[1 + k] = re;
    sim[1 + k] = im;
  }
  if (tid == 0) { sre[0] = 0.f; sim[0] = 0.f; sre[NF + 1] = 0.f; sim[NF + 1] = 0.f; }
  __syncthreads();

  // conv1: (f,2) -> (f,4), k=3 same, relu
  for (int f = tid; f < NF; f += 256) {
    float acc[4] = {wb1[0], wb1[1], wb1[2], wb1[3]};
    #pragma unroll
    for (int i = 0; i < 3; ++i) {
      float vr = sre[f + i], vi = sim[f + i];
      #pragma unroll
      for (int c = 0; c < 4; ++c)
        acc[c] = fmaf(vr, wW1[(i*2+0)*4 + c], fmaf(vi, wW1[(i*2+1)*4 + c], acc[c]));
    }
    #pragma unroll
    for (int c = 0; c < 4; ++c) h1[c][f + 1] = fmaxf(acc[c], 0.f);
  }
  if (tid < 4) { h1[tid][0] = 0.f; h1[tid][NF + 1] = 0.f; }
  __syncthreads();

  // conv2: (f,4) -> (f,8), k=3 same, outer relu, store channel-major + stats
  const size_t obase = (size_t)bt * FRS;
  float ps1 = 0.f, ps2 = 0.f;
  for (int f = tid; f < NF; f += 256) {
    float acc[8];
    #pragma unroll
    for (int c = 0; c < 8; ++c) acc[c] = wb2[c];
    #pragma unroll
    for (int i = 0; i < 3; ++i)
      #pragma unroll
      for (int c4 = 0; c4 < 4; ++c4) {
        float hv = h1[c4][f + i];
        #pragma unroll
        for (int c = 0; c < 8; ++c)
          acc[c] = fmaf(hv, wW2[(i*4+c4)*8 + c], acc[c]);
      }
    #pragma unroll
    for (int c = 0; c < 8; ++c) {
      float v = fmaxf(acc[c], 0.f);
      H[obase + (size_t)c * NF + f] = v;
      ps1 += v;
      ps2 = fmaf(v, v, ps2);
    }
  }
  #pragma unroll
  for (int off = 32; off > 0; off >>= 1) {
    ps1 += __shfl_down(ps1, off, 64);
    ps2 += __shfl_down(ps2, off, 64);
  }
  if ((tid & 63) == 0) { red[(tid >> 6) * 2] = ps1; red[(tid >> 6) * 2 + 1] = ps2; }
  __syncthreads();
  if (tid == 0) {
    stats0[bt * 2]     = red[0] + red[2] + red[4] + red[6];
    stats0[bt * 2 + 1] = red[1] + red[3] + red[5] + red[7];
  }
}

// ---------------------------------------------------------------------------
// Transpose LN/depthwise tables to flat channel-major [c][f] (NF stride).
// dst layout: [0,NEL) gT, [NEL,2NEL) bnT, [2NEL,5NEL) dwT[dt][c][f]
// ---------------------------------------------------------------------------
template<int CIN>
__global__ __launch_bounds__(256) void transpose_tbl(
    const float* __restrict__ g, const float* __restrict__ bn,
    const float* __restrict__ dw, float* __restrict__ dst)
{
  constexpr int NEL = CIN * NF;
  int idx = blockIdx.x * 256 + threadIdx.x;
  if (idx < NEL) {
    int c = idx / NF, f = idx - c * NF;
    dst[idx] = g[f * CIN + c];
  } else if (idx < 2 * NEL) {
    int r = idx - NEL;
    int c = r / NF, f = r - c * NF;
    dst[idx] = bn[f * CIN + c];
  } else if (idx < 5 * NEL) {
    int r = idx - 2 * NEL;
    int dt = r / NEL, r2 = r - dt * NEL;
    int c = r2 / NF, f = r2 - c * NF;
    dst[idx] = dw[(f * CIN + c) * 3 + dt];
  }
}

// ---------------------------------------------------------------------------
// Strip layer kernel: one block per (b, strip of TS frames). Keeps the
// 3-frame normalized sliding window in registers (flattened element/thread),
// so each H frame is read from global exactly once per block.
// HEAD fuses fc1/fc2/sigmoid via LDS partial-product scatter (pc).
// ---------------------------------------------------------------------------
template<int CIN, bool HEAD>
__global__ __launch_bounds__(256) void layer_strip(
    const float* __restrict__ H, float* __restrict__ Hout,
    const float* __restrict__ st0, const float* __restrict__ st1,
    const float* __restrict__ st2, float* __restrict__ stats_out,
    const float* __restrict__ tbl,
    const float* __restrict__ W1g, const float* __restrict__ b1g,
    const float* __restrict__ W2g, const float* __restrict__ b2g,
    const float* __restrict__ fc1W, const float* __restrict__ fc1b,
    const float* __restrict__ fc2W, const float* __restrict__ fc2b,
    float* __restrict__ out)
{
  constexpr int NEL  = CIN * NF;            // 2056 / 4112 / 6168
  constexpr int NPER = (NEL + 255) / 256;   // 9 / 17 / 25
  constexpr int TAIL = NEL - 256 * (NPER - 1);  // == CIN

  __shared__ float y[CIN * 259];            // depthwise out, padded rows
  __shared__ float h1[8 * 259];             // conv1 out, padded rows
  __shared__ float wW1[3 * CIN * 8], wb1[8], wW2[192], wb2[8];
  __shared__ float red[8];
  __shared__ float pcbuf[HEAD ? 2 * 3 * 260 : 1];  // fc1 partials, dbuf
  __shared__ float wfc1[HEAD ? 96 : 1];

  const int tid   = threadIdx.x;
  const int blk   = blockIdx.x;
  const int b     = blk / SPB;
  const int strip = blk - b * SPB;
  const int s0    = strip * TS;
  const int tend  = min(s0 + TS, TT);

  for (int i = tid; i < 3 * CIN * 8; i += 256) wW1[i] = W1g[i];
  if (tid < 192) wW2[tid] = W2g[tid];
  if (tid < 8) { wb1[tid] = b1g[tid]; wb2[tid] = b2g[tid]; }
  if (tid < CIN) { y[tid * 259] = 0.f; y[tid * 259 + 258] = 0.f; }
  if (tid < 8)   { h1[tid * 259] = 0.f; h1[tid * 259 + 258] = 0.f; }
  if constexpr (HEAD) {
    if (tid < 96) wfc1[tid] = fc1W[tid];
    for (int i = tid; i < 2 * 3 * 260; i += 256) pcbuf[i] = 0.f;
  }
  __syncthreads();

  const float* gT  = tbl;
  const float* bnT = tbl + NEL;
  const float* dwT = tbl + 2 * NEL;

  float w0[NPER], w1[NPER], w2[NPER];
  #pragma unroll
  for (int j = 0; j < NPER; ++j) { w0[j] = 0.f; w1[j] = 0.f; w2[j] = 0.f; }

  for (int t = s0 - 2; t < tend; ++t) {
    const int fb = b * TT + t;
    const int p  = (t - s0) & 1;             // pc slot (output steps only)
    float* pcw = nullptr;
    if constexpr (HEAD) pcw = pcbuf + p * 780;

    // ---- stage A: rotate window, load+LN frame t, depthwise into y ----
    float mu = 0.f, rs = 0.f;
    if (t >= 0) {
      float s1 = st0[fb * 2], s2 = st0[fb * 2 + 1];
      if constexpr (CIN >= 16) { s1 += st1[fb * 2]; s2 += st1[fb * 2 + 1]; }
      if constexpr (CIN >= 24) { s1 += st2[fb * 2]; s2 += st2[fb * 2 + 1]; }
      const float m = s1 * (1.0f / NEL);
      mu = m;
      rs = rsqrtf(s2 * (1.0f / NEL) - m * m + EPS);
    }
    const float* Hf = H + (size_t)fb * FRS;
    const bool emit = (t >= s0);

    #pragma unroll
    for (int j = 0; j < NPER; ++j) {
      const bool act = (j < NPER - 1) || (tid < TAIL);
      int f, c;
      if (tid >= j) { f = tid - j; c = j; } else { f = tid - j + 257; c = j - 1; }
      const int idx = tid + 256 * j;
      // rotate
      w0[j] = w1[j];
      w1[j] = w2[j];
      float xn = 0.f;
      if (t >= 0 && act) {
        const float xr = Hf[idx];
        if constexpr (HEAD) {
          if (emit) {   // fc1 x-part partial products (raw input)
            atomicAdd(&pcw[0 * 260 + f], xr * wfc1[0 * 32 + c]);
            atomicAdd(&pcw[1 * 260 + f], xr * wfc1[1 * 32 + c]);
            atomicAdd(&pcw[2 * 260 + f], xr * wfc1[2 * 32 + c]);
          }
        }
        xn = fmaf((xr - mu) * rs, gT[idx], bnT[idx]);
      }
      w2[j] = xn;
      if (emit && act) {
        float yv = w0[j] * dwT[idx];
        yv = fmaf(w1[j], dwT[NEL + idx], yv);
        yv = fmaf(w2[j], dwT[2 * NEL + idx], yv);
        y[c * 259 + 1 + f] = yv;
      }
    }
    if (!emit) continue;   // halo step (uniform): window filled, no output
    __syncthreads();

    // ---- stage B: conv1 (f,CIN)->(f,8), k=3 same, relu ----
    {
      const int f = tid;
      float acc[8];
      #pragma unroll
      for (int c = 0; c < 8; ++c) acc[c] = wb1[c];
      #pragma unroll
      for (int i = 0; i < 3; ++i)
        for (int cin = 0; cin < CIN; ++cin) {
          const float yv = y[cin * 259 + f + i];
          #pragma unroll
          for (int c = 0; c < 8; ++c)
            acc[c] = fmaf(yv, wW1[(i * CIN + cin) * 8 + c], acc[c]);
        }
      #pragma unroll
      for (int c = 0; c < 8; ++c) h1[c * 259 + 1 + f] = fmaxf(acc[c], 0.f);
      if (tid < 8) {   // sidecar: bin 256, out-channel = tid
        float a = wb1[tid];
        #pragma unroll
        for (int i = 0; i < 3; ++i)
          for (int cin = 0; cin < CIN; ++cin)
            a = fmaf(y[cin * 259 + 256 + i], wW1[(i * CIN + cin) * 8 + tid], a);
        h1[tid * 259 + 257] = fmaxf(a, 0.f);
      }
    }
    __syncthreads();

    // ---- stage C: conv2 (f,8)->(f,8), relu; store / fc1 partials ----
    float ps1 = 0.f, ps2 = 0.f;
    {
      const int f = tid;
      float o2[8];
      #pragma unroll
      for (int c = 0; c < 8; ++c) o2[c] = wb2[c];
      #pragma unroll
      for (int i = 0; i < 3; ++i)
        #pragma unroll
        for (int c8 = 0; c8 < 8; ++c8) {
          const float hv = h1[c8 * 259 + f + i];
          #pragma unroll
          for (int c = 0; c < 8; ++c)
            o2[c] = fmaf(hv, wW2[(i * 8 + c8) * 8 + c], o2[c]);
        }
      #pragma unroll
      for (int c = 0; c < 8; ++c) o2[c] = fmaxf(o2[c], 0.f);

      if constexpr (!HEAD) {
        const size_t ob = (size_t)fb * FRS + (size_t)CIN * NF;
        #pragma unroll
        for (int c = 0; c < 8; ++c) {
          Hout[ob + (size_t)c * NF + f] = o2[c];
          ps1 += o2[c];
          ps2 = fmaf(o2[c], o2[c], ps2);
        }
        if (tid >= 8 && tid < 16) {   // sidecar: bin 256, ch = tid-8
          const int c8 = tid - 8;
          float a = wb2[c8];
          #pragma unroll
          for (int i = 0; i < 3; ++i)
            #pragma unroll
            for (int cp = 0; cp < 8; ++cp)
              a = fmaf(h1[cp * 259 + 256 + i], wW2[(i * 8 + cp) * 8 + c8], a);
          const float v = fmaxf(a, 0.f);
          Hout[ob + (size_t)c8 * NF + 256] = v;
          ps1 += v;
          ps2 = fmaf(v, v, ps2);
        }
      } else {
        #pragma unroll
        for (int i = 0; i < 3; ++i) {
          float v = 0.f;
          #pragma unroll
          for (int c8 = 0; c8 < 8; ++c8)
            v = fmaf(o2[c8], wfc1[i * 32 + 24 + c8], v);
          pcw[i * 260 + f] += v;    // A-stage atomics already barriered
        }
        if (tid >= 8 && tid < 16) {   // sidecar: bin 256
          const int c8 = tid - 8;
          float a = wb2[c8];
          #pragma unroll
          for (int i = 0; i < 3; ++i)
            #pragma unroll
            for (int cp = 0; cp < 8; ++cp)
              a = fmaf(h1[cp * 259 + 256 + i], wW2[(i * 8 + cp) * 8 + c8], a);
          const float v = fmaxf(a, 0.f);
          #pragma unroll
          for (int i = 0; i < 3; ++i)
            atomicAdd(&pcw[i * 260 + 256], v * wfc1[i * 32 + 24 + c8]);
        }
        // zero the other pc slot for the next output step
        float* pz = pcbuf + (p ^ 1) * 780;
        for (int i2 = tid; i2 < 780; i2 += 256) pz[i2] = 0.f;
      }
    }

    if constexpr (!HEAD) {
      // per-frame LN partial stats of these 8 output channels
      #pragma unroll
      for (int off = 32; off > 0; off >>= 1) {
        ps1 += __shfl_down(ps1, off, 64);
        ps2 += __shfl_down(ps2, off, 64);
      }
      if ((tid & 63) == 0) { red[(tid >> 6) * 2] = ps1; red[(tid >> 6) * 2 + 1] = ps2; }
      __syncthreads();
      if (tid == 0) {
        stats_out[fb * 2]     = red[0] + red[2] + red[4] + red[6];
        stats_out[fb * 2 + 1] = red[1] + red[3] + red[5] + red[7];
      }
    } else {
      __syncthreads();   // pc complete
      // ---- stage D: fc1 (valid k=3) + relu + fc2 + sigmoid ----
      float part = 0.f;
      if (tid < NF - 2) {
        const float* pcr = pcbuf + p * 780;
        float v = pcr[tid] + pcr[260 + tid + 1] + pcr[520 + tid + 2] + fc1b[0];
        v = fmaxf(v, 0.f);
        part = v * fc2W[tid];
      }
      #pragma unroll
      for (int off = 32; off > 0; off >>= 1) part += __shfl_down(part, off, 64);
      if ((tid & 63) == 0) red[tid >> 6] = part;
      __syncthreads();
      if (tid == 0) {
        const float tot = red[0] + red[1] + red[2] + red[3] + fc2b[0];
        out[fb] = 1.0f / (1.0f + expf(-tot));
      }
    }
  }
}

}  // namespace

extern "C" void kernel_launch(void* const* d_in, const int* in_sizes, int n_in,
                              void* d_out, int out_size, void* d_ws, size_t ws_size,
                              hipStream_t stream) {
  (void)in_sizes; (void)n_in; (void)out_size; (void)ws_size;
  const float* x = (const float*)d_in[0];
  float* out = (float*)d_out;
  float* ws  = (float*)d_ws;

  const size_t Hsz = (size_t)NBT * FRS;   // 50,478,912 floats
  float* H    = ws;
  float* st0  = H + Hsz;
  float* st1  = st0 + 2 * NBT;
  float* st2  = st1 + 2 * NBT;
  float* tbl1 = st2 + 2 * NBT;
  float* tbl2 = tbl1 + 5 * (8 * NF);
  float* tbl3 = tbl2 + 5 * (16 * NF);

  dim3 blk(256);
  const int nstrip = BATCH * SPB;   // 912

  transpose_tbl<8><<<dim3((5 * 8 * NF + 255) / 256), blk, 0, stream>>>(
      (const float*)d_in[5], (const float*)d_in[6], (const float*)d_in[7], tbl1);
  transpose_tbl<16><<<dim3((5 * 16 * NF + 255) / 256), blk, 0, stream>>>(
      (const float*)d_in[12], (const float*)d_in[13], (const float*)d_in[14], tbl2);
  transpose_tbl<24><<<dim3((5 * 24 * NF + 255) / 256), blk, 0, stream>>>(
      (const float*)d_in[19], (const float*)d_in[20], (const float*)d_in[21], tbl3);

  stft_l0_kernel<<<dim3(NBT), blk, 0, stream>>>(
      x, (const float*)d_in[1], (const float*)d_in[2],
      (const float*)d_in[3], (const float*)d_in[4], H, st0);

  layer_strip<8, false><<<dim3(nstrip), blk, 0, stream>>>(
      H, H, st0, nullptr, nullptr, st1, tbl1,
      (const float*)d_in[8], (const float*)d_in[9],
      (const float*)d_in[10], (const float*)d_in[11],
      nullptr, nullptr, nullptr, nullptr, nullptr);

  layer_strip<16, false><<<dim3(nstrip), blk, 0, stream>>>(
      H, H, st0, st1, nullptr, st2, tbl2,
      (const float*)d_in[15], (const float*)d_in[16],
      (const float*)d_in[17], (const float*)d_in[18],
      nullptr, nullptr, nullptr, nullptr, nullptr);

  layer_strip<24, true><<<dim3(nstrip), blk, 0, stream>>>(
      H, nullptr, st0, st1, st2, nullptr, tbl3,
      (const float*)d_in[22], (const float*)d_in[23],
      (const float*)d_in[24], (const float*)d_in[25],
      (const float*)d_in[26], (const float*)d_in[27],
      (const float*)d_in[28], (const float*)d_in[29],
      out);
}

// Round 4
// 523.389 us; speedup vs baseline: 5.2625x; 4.6384x over previous
//
#include <hip/hip_runtime.h>

namespace {

constexpr int BATCH = 8;
constexpr int SLEN  = 262144;
constexpr int TT    = 1023;   // (262144-512)/256 + 1
constexpr int NF    = 257;    // rfft bins
constexpr int NCH   = 24;     // channels stored in H
constexpr int NBT   = BATCH * TT;   // 8184
constexpr int FRS   = NCH * NF;     // frame stride (6168 floats)
constexpr float EPS = 1e-5f;

// ---------------------------------------------------------------------------
// Kernel A: STFT (hann, 512-pt rfft) + l0 TD block. One workgroup per (b,t).
// DFT inner loop: per-lane twiddle recurrence (4 independent chains, no LDS
// gather); ab[n] accesses are wave-uniform -> LDS broadcast, conflict-free.
// Writes H channels 0..7 + LN partial stats st0.
// ---------------------------------------------------------------------------
__global__ __launch_bounds__(256) void stft_l0_kernel(
    const float* __restrict__ x,
    const float* __restrict__ W1g, const float* __restrict__ b1g,
    const float* __restrict__ W2g, const float* __restrict__ b2g,
    float* __restrict__ H, float* __restrict__ stats0)
{
  __shared__ float  xw[512];     // windowed frame
  __shared__ float2 ab[256];     // {xw[n]+xw[512-n], xw[n]-xw[512-n]}, ab[0]=0
  __shared__ float  sre[NF + 2];
  __shared__ float  sim[NF + 2];
  __shared__ float  h1[4][NF + 2];
  __shared__ float  wW1[24], wb1[4], wW2[96], wb2[8];
  __shared__ float  red[8];

  const int tid = threadIdx.x;
  const int bt  = blockIdx.x;
  const int b   = bt / TT;
  const int t   = bt - b * TT;
  const float* xp = x + (size_t)b * SLEN + (size_t)t * 256;

  if (tid < 24) wW1[tid] = W1g[tid];
  if (tid < 4)  wb1[tid] = b1g[tid];
  if (tid < 96) wW2[tid] = W2g[tid];
  if (tid < 8)  wb2[tid] = b2g[tid];

  const float STEP = 6.283185307179586f / 512.0f;
  for (int n = tid; n < 512; n += 256) {
    float sv, cv;
    sincosf(STEP * (float)n, &sv, &cv);
    xw[n] = xp[n] * (0.5f - 0.5f * cv);   // hann window
  }
  __syncthreads();

  if (tid == 0) ab[0] = make_float2(0.f, 0.f);
  if (tid >= 1) {  // n = 1..255
    float u = xw[tid], v = xw[512 - tid];
    ab[tid] = make_float2(u + v, u - v);
  }
  __syncthreads();

  const float x0 = xw[0], x256 = xw[256];

  // ---- main DFT: lane k = tid (0..255), 4-chain twiddle recurrence ----
  {
    const int k = tid;
    float s1, c1;
    sincosf(STEP * (float)k, &s1, &c1);          // w = e^{i*theta}
    const float c2 = fmaf(c1, c1, -s1 * s1), s2 = 2.f * c1 * s1;       // w^2
    const float c3 = fmaf(c2, c1, -s2 * s1), s3 = fmaf(c2, s1, s2 * c1); // w^3
    const float c4 = fmaf(c2, c2, -s2 * s2), s4 = 2.f * c2 * s2;       // w^4
    float cA = 1.f, sA = 0.f;   // chain n = 4m
    float cB = c1,  sB = s1;    // chain n = 4m+1
    float cC = c2,  sC = s2;    // chain n = 4m+2
    float cD = c3,  sD = s3;    // chain n = 4m+3
    float re = x0 + ((k & 1) ? -x256 : x256);
    float im = 0.f;
    for (int m = 0; m < 64; ++m) {
      const float2 p0 = ab[4*m],     p1 = ab[4*m + 1];
      const float2 p2 = ab[4*m + 2], p3 = ab[4*m + 3];
      re = fmaf(p0.x, cA, re); im = fmaf(-p0.y, sA, im);
      re = fmaf(p1.x, cB, re); im = fmaf(-p1.y, sB, im);
      re = fmaf(p2.x, cC, re); im = fmaf(-p2.y, sC, im);
      re = fmaf(p3.x, cD, re); im = fmaf(-p3.y, sD, im);
      float t0;
      t0 = fmaf(cA, c4, -sA * s4); sA = fmaf(cA, s4, sA * c4); cA = t0;
      t0 = fmaf(cB, c4, -sB * s4); sB = fmaf(cB, s4, sB * c4); cB = t0;
      t0 = fmaf(cC, c4, -sC * s4); sC = fmaf(cC, s4, sC * c4); cC = t0;
      t0 = fmaf(cD, c4, -sD * s4); sD = fmaf(cD, s4, sD * c4); cD = t0;
    }
    sre[1 + k] = re;
    sim[1 + k] = im;
  }

  // ---- bin 256: re = x0 + x256 + sum (-1)^n ab[n].x ; im = 0 ----
  {
    float ps = 0.f;
    if (tid >= 1) ps = (tid & 1) ? -ab[tid].x : ab[tid].x;
    #pragma unroll
    for (int off = 32; off > 0; off >>= 1) ps += __shfl_down(ps, off, 64);
    if ((tid & 63) == 0) red[tid >> 6] = ps;
    __syncthreads();
    if (tid == 0) {
      sre[257] = x0 + x256 + red[0] + red[1] + red[2] + red[3];
      sim[257] = 0.f;
      sre[0] = 0.f; sim[0] = 0.f; sre[258] = 0.f; sim[258] = 0.f;
    }
  }
  __syncthreads();

  // conv1: (f,2) -> (f,4), k=3 same, relu
  for (int f = tid; f < NF; f += 256) {
    float acc[4] = {wb1[0], wb1[1], wb1[2], wb1[3]};
    #pragma unroll
    for (int i = 0; i < 3; ++i) {
      float vr = sre[f + i], vi = sim[f + i];
      #pragma unroll
      for (int c = 0; c < 4; ++c)
        acc[c] = fmaf(vr, wW1[(i*2+0)*4 + c], fmaf(vi, wW1[(i*2+1)*4 + c], acc[c]));
    }
    #pragma unroll
    for (int c = 0; c < 4; ++c) h1[c][f + 1] = fmaxf(acc[c], 0.f);
  }
  if (tid < 4) { h1[tid][0] = 0.f; h1[tid][NF + 1] = 0.f; }
  __syncthreads();

  // conv2: (f,4) -> (f,8), k=3 same, outer relu, store channel-major + stats
  const size_t obase = (size_t)bt * FRS;
  float ps1 = 0.f, ps2 = 0.f;
  for (int f = tid; f < NF; f += 256) {
    float acc[8];
    #pragma unroll
    for (int c = 0; c < 8; ++c) acc[c] = wb2[c];
    #pragma unroll
    for (int i = 0; i < 3; ++i)
      #pragma unroll
      for (int c4 = 0; c4 < 4; ++c4) {
        float hv = h1[c4][f + i];
        #pragma unroll
        for (int c = 0; c < 8; ++c)
          acc[c] = fmaf(hv, wW2[(i*4+c4)*8 + c], acc[c]);
      }
    #pragma unroll
    for (int c = 0; c < 8; ++c) {
      float v = fmaxf(acc[c], 0.f);
      H[obase + (size_t)c * NF + f] = v;
      ps1 += v;
      ps2 = fmaf(v, v, ps2);
    }
  }
  #pragma unroll
  for (int off = 32; off > 0; off >>= 1) {
    ps1 += __shfl_down(ps1, off, 64);
    ps2 += __shfl_down(ps2, off, 64);
  }
  if ((tid & 63) == 0) { red[(tid >> 6) * 2] = ps1; red[(tid >> 6) * 2 + 1] = ps2; }
  __syncthreads();
  if (tid == 0) {
    stats0[bt * 2]     = red[0] + red[2] + red[4] + red[6];
    stats0[bt * 2 + 1] = red[1] + red[3] + red[5] + red[7];
  }
}

// ---------------------------------------------------------------------------
// Transpose LN/depthwise tables to flat channel-major [c][f] (NF stride).
// dst layout: [0,NEL) gT, [NEL,2NEL) bnT, [2NEL,5NEL) dwT[dt][c][f]
// ---------------------------------------------------------------------------
template<int CIN>
__global__ __launch_bounds__(256) void transpose_tbl(
    const float* __restrict__ g, const float* __restrict__ bn,
    const float* __restrict__ dw, float* __restrict__ dst)
{
  constexpr int NEL = CIN * NF;
  int idx = blockIdx.x * 256 + threadIdx.x;
  if (idx < NEL) {
    int c = idx / NF, f = idx - c * NF;
    dst[idx] = g[f * CIN + c];
  } else if (idx < 2 * NEL) {
    int r = idx - NEL;
    int c = r / NF, f = r - c * NF;
    dst[idx] = bn[f * CIN + c];
  } else if (idx < 5 * NEL) {
    int r = idx - 2 * NEL;
    int dt = r / NEL, r2 = r - dt * NEL;
    int c = r2 / NF, f = r2 - c * NF;
    dst[idx] = dw[(f * CIN + c) * 3 + dt];
  }
}

// ---------------------------------------------------------------------------
// Layer kernel, one block per (b,t). LN stats precomputed by producers.
// Stage A: read frames t-2..t (L2-warm, adjacent blocks share), normalize,
// depthwise -> y in LDS. Stage B: conv1. Stage C: conv2 (+store+stats or
// head fc1/fc2/sigmoid with L1-warm raw-frame re-read).
// ---------------------------------------------------------------------------
template<int CIN, bool HEAD>
__global__ __launch_bounds__(256, 4) void layer_bt(
    const float* __restrict__ H, float* __restrict__ Hout,
    const float* __restrict__ st0, const float* __restrict__ st1,
    const float* __restrict__ st2, float* __restrict__ stats_out,
    const float* __restrict__ tbl,
    const float* __restrict__ W1g, const float* __restrict__ b1g,
    const float* __restrict__ W2g, const float* __restrict__ b2g,
    const float* __restrict__ fc1W, const float* __restrict__ fc1b,
    const float* __restrict__ fc2W, const float* __restrict__ fc2b,
    float* __restrict__ out)
{
  constexpr int NEL  = CIN * NF;               // 2056 / 4112 / 6168
  constexpr int NPER = (NEL + 255) / 256;      // 9 / 17 / 25
  constexpr int TAIL = NEL - 256 * (NPER - 1); // == CIN

  __shared__ float y[CIN * 259];     // depthwise out, padded rows (reused as out2)
  __shared__ float h1[8 * 259];      // conv1 out, padded rows
  __shared__ float wW1[3 * CIN * 8], wb1[8], wW2[192], wb2[8];
  __shared__ float red[8];
  __shared__ float wfc1[HEAD ? 96 : 1];

  const int tid = threadIdx.x;
  const int bt  = blockIdx.x;
  const int b   = bt / TT;
  const int t   = bt - b * TT;

  for (int i = tid; i < 3 * CIN * 8; i += 256) wW1[i] = W1g[i];
  if (tid < 192) wW2[tid] = W2g[tid];
  if (tid < 8) { wb1[tid] = b1g[tid]; wb2[tid] = b2g[tid]; }
  if (tid < CIN) { y[tid * 259] = 0.f; y[tid * 259 + 258] = 0.f; }
  if (tid < 8)   { h1[tid * 259] = 0.f; h1[tid * 259 + 258] = 0.f; }
  if constexpr (HEAD) { if (tid < 96) wfc1[tid] = fc1W[tid]; }

  // per-frame LN stats from producer partials (wave-uniform scalar loads)
  float mu0 = 0.f, rs0 = 0.f, mu1 = 0.f, rs1 = 0.f, mu2, rs2;
  {
    const float inv = 1.0f / (float)NEL;
    const int fb = bt;
    float s1 = st0[fb * 2], s2v = st0[fb * 2 + 1];
    if constexpr (CIN >= 16) { s1 += st1[fb * 2]; s2v += st1[fb * 2 + 1]; }
    if constexpr (CIN >= 24) { s1 += st2[fb * 2]; s2v += st2[fb * 2 + 1]; }
    mu2 = s1 * inv; rs2 = rsqrtf(s2v * inv - mu2 * mu2 + EPS);
    if (t >= 1) {
      const int f1b = bt - 1;
      float a = st0[f1b * 2], c = st0[f1b * 2 + 1];
      if constexpr (CIN >= 16) { a += st1[f1b * 2]; c += st1[f1b * 2 + 1]; }
      if constexpr (CIN >= 24) { a += st2[f1b * 2]; c += st2[f1b * 2 + 1]; }
      mu1 = a * inv; rs1 = rsqrtf(c * inv - mu1 * mu1 + EPS);
    }
    if (t >= 2) {
      const int f0b = bt - 2;
      float a = st0[f0b * 2], c = st0[f0b * 2 + 1];
      if constexpr (CIN >= 16) { a += st1[f0b * 2]; c += st1[f0b * 2 + 1]; }
      if constexpr (CIN >= 24) { a += st2[f0b * 2]; c += st2[f0b * 2 + 1]; }
      mu0 = a * inv; rs0 = rsqrtf(c * inv - mu0 * mu0 + EPS);
    }
  }

  const float* gT  = tbl;
  const float* bnT = tbl + NEL;
  const float* dwT = tbl + 2 * NEL;
  const float* f2 = H + (size_t)bt * FRS;
  const float* f1 = f2 - FRS;
  const float* f0 = f2 - 2 * FRS;

  // ---- stage A: LN + causal depthwise into y ----
  if (t >= 2) {
    #pragma unroll
    for (int j = 0; j < NPER; ++j) {
      const bool act = (j < NPER - 1) || (tid < TAIL);
      if (act) {
        const int idx = tid + 256 * j;
        const float gv = gT[idx], bv = bnT[idx];
        float yv = fmaf(fmaf((f0[idx] - mu0) * rs0, gv, bv), dwT[idx], 0.f);
        yv = fmaf(fmaf((f1[idx] - mu1) * rs1, gv, bv), dwT[NEL + idx], yv);
        yv = fmaf(fmaf((f2[idx] - mu2) * rs2, gv, bv), dwT[2 * NEL + idx], yv);
        int f, c;
        if (tid >= j) { f = tid - j; c = j; } else { f = tid - j + 257; c = j - 1; }
        y[c * 259 + 1 + f] = yv;
      }
    }
  } else {  // t == 0 or 1: missing frames contribute exactly 0 (post-LN pad)
    #pragma unroll
    for (int j = 0; j < NPER; ++j) {
      const bool act = (j < NPER - 1) || (tid < TAIL);
      if (act) {
        const int idx = tid + 256 * j;
        const float gv = gT[idx], bv = bnT[idx];
        float yv = 0.f;
        if (t >= 1)
          yv = fmaf(fmaf((f1[idx] - mu1) * rs1, gv, bv), dwT[NEL + idx], yv);
        yv = fmaf(fmaf((f2[idx] - mu2) * rs2, gv, bv), dwT[2 * NEL + idx], yv);
        int f, c;
        if (tid >= j) { f = tid - j; c = j; } else { f = tid - j + 257; c = j - 1; }
        y[c * 259 + 1 + f] = yv;
      }
    }
  }
  __syncthreads();

  // ---- stage B: conv1 (f,CIN)->(f,8), k=3 same, relu ----
  {
    const int f = tid;  // 0..255
    float acc[8];
    #pragma unroll
    for (int c = 0; c < 8; ++c) acc[c] = wb1[c];
    #pragma unroll
    for (int i = 0; i < 3; ++i)
      for (int cin = 0; cin < CIN; ++cin) {
        const float yv = y[cin * 259 + f + i];
        #pragma unroll
        for (int c = 0; c < 8; ++c)
          acc[c] = fmaf(yv, wW1[(i * CIN + cin) * 8 + c], acc[c]);
      }
    #pragma unroll
    for (int c = 0; c < 8; ++c) h1[c * 259 + 1 + f] = fmaxf(acc[c], 0.f);
  }
  if (tid < 8) {  // sidecar: bin 256, out-channel = tid
    float a = wb1[tid];
    #pragma unroll
    for (int i = 0; i < 3; ++i)
      for (int cin = 0; cin < CIN; ++cin)
        a = fmaf(y[cin * 259 + 256 + i], wW1[(i * CIN + cin) * 8 + tid], a);
    h1[tid * 259 + 257] = fmaxf(a, 0.f);
  }
  __syncthreads();

  // ---- stage C: conv2 (f,8)->(f,8), k=3 same, relu ----
  float* out2 = y;  // y dead after conv1; reuse as out2[c*257+f] (HEAD)
  float ps1 = 0.f, ps2 = 0.f;
  {
    const int f = tid;
    float o2[8];
    #pragma unroll
    for (int c = 0; c < 8; ++c) o2[c] = wb2[c];
    #pragma unroll
    for (int i = 0; i < 3; ++i)
      #pragma unroll
      for (int c8 = 0; c8 < 8; ++c8) {
        const float hv = h1[c8 * 259 + f + i];
        #pragma unroll
        for (int c = 0; c < 8; ++c)
          o2[c] = fmaf(hv, wW2[(i * 8 + c8) * 8 + c], o2[c]);
      }
    #pragma unroll
    for (int c = 0; c < 8; ++c) o2[c] = fmaxf(o2[c], 0.f);

    if constexpr (!HEAD) {
      const size_t ob = (size_t)bt * FRS + (size_t)CIN * NF;
      #pragma unroll
      for (int c = 0; c < 8; ++c) {
        Hout[ob + (size_t)c * NF + f] = o2[c];
        ps1 += o2[c];
        ps2 = fmaf(o2[c], o2[c], ps2);
      }
    } else {
      #pragma unroll
      for (int c = 0; c < 8; ++c) out2[c * 257 + f] = o2[c];
    }
  }
  if (tid >= 8 && tid < 16) {  // sidecar: bin 256, ch = tid-8
    const int c8 = tid - 8;
    float a = wb2[c8];
    #pragma unroll
    for (int i = 0; i < 3; ++i)
      #pragma unroll
      for (int cp = 0; cp < 8; ++cp)
        a = fmaf(h1[cp * 259 + 256 + i], wW2[(i * 8 + cp) * 8 + c8], a);
    const float v = fmaxf(a, 0.f);
    if constexpr (!HEAD) {
      const size_t ob = (size_t)bt * FRS + (size_t)CIN * NF;
      Hout[ob + (size_t)c8 * NF + 256] = v;
      ps1 += v;
      ps2 = fmaf(v, v, ps2);
    } else {
      out2[c8 * 257 + 256] = v;
    }
  }

  if constexpr (!HEAD) {
    #pragma unroll
    for (int off = 32; off > 0; off >>= 1) {
      ps1 += __shfl_down(ps1, off, 64);
      ps2 += __shfl_down(ps2, off, 64);
    }
    if ((tid & 63) == 0) { red[(tid >> 6) * 2] = ps1; red[(tid >> 6) * 2 + 1] = ps2; }
    __syncthreads();
    if (tid == 0) {
      stats_out[bt * 2]     = red[0] + red[2] + red[4] + red[6];
      stats_out[bt * 2 + 1] = red[1] + red[3] + red[5] + red[7];
    }
  } else {
    __syncthreads();  // out2 complete
    // ---- stage D: fc1 (valid k=3, 32ch) + relu + fc2 + sigmoid ----
    float part = 0.f;
    if (tid < NF - 2) {
      const float* xg = f2;  // raw frame t, L1/L2-warm (stage A just read it)
      float acc = fc1b[0];
      #pragma unroll
      for (int i = 0; i < 3; ++i) {
        for (int c = 0; c < 24; ++c)
          acc = fmaf(xg[c * 257 + tid + i], wfc1[i * 32 + c], acc);
        #pragma unroll
        for (int c8 = 0; c8 < 8; ++c8)
          acc = fmaf(out2[c8 * 257 + tid + i], wfc1[i * 32 + 24 + c8], acc);
      }
      part = fmaxf(acc, 0.f) * fc2W[tid];
    }
    #pragma unroll
    for (int off = 32; off > 0; off >>= 1) part += __shfl_down(part, off, 64);
    if ((tid & 63) == 0) red[tid >> 6] = part;
    __syncthreads();
    if (tid == 0) {
      const float tot = red[0] + red[1] + red[2] + red[3] + fc2b[0];
      out[bt] = 1.0f / (1.0f + expf(-tot));
    }
  }
}

}  // namespace

extern "C" void kernel_launch(void* const* d_in, const int* in_sizes, int n_in,
                              void* d_out, int out_size, void* d_ws, size_t ws_size,
                              hipStream_t stream) {
  (void)in_sizes; (void)n_in; (void)out_size; (void)ws_size;
  const float* x = (const float*)d_in[0];
  float* out = (float*)d_out;
  float* ws  = (float*)d_ws;

  const size_t Hsz = (size_t)NBT * FRS;   // 50,478,912 floats
  float* H    = ws;
  float* st0  = H + Hsz;
  float* st1  = st0 + 2 * NBT;
  float* st2  = st1 + 2 * NBT;
  float* tbl1 = st2 + 2 * NBT;
  float* tbl2 = tbl1 + 5 * (8 * NF);
  float* tbl3 = tbl2 + 5 * (16 * NF);

  dim3 blk(256);

  transpose_tbl<8><<<dim3((5 * 8 * NF + 255) / 256), blk, 0, stream>>>(
      (const float*)d_in[5], (const float*)d_in[6], (const float*)d_in[7], tbl1);
  transpose_tbl<16><<<dim3((5 * 16 * NF + 255) / 256), blk, 0, stream>>>(
      (const float*)d_in[12], (const float*)d_in[13], (const float*)d_in[14], tbl2);
  transpose_tbl<24><<<dim3((5 * 24 * NF + 255) / 256), blk, 0, stream>>>(
      (const float*)d_in[19], (const float*)d_in[20], (const float*)d_in[21], tbl3);

  stft_l0_kernel<<<dim3(NBT), blk, 0, stream>>>(
      x, (const float*)d_in[1], (const float*)d_in[2],
      (const float*)d_in[3], (const float*)d_in[4], H, st0);

  layer_bt<8, false><<<dim3(NBT), blk, 0, stream>>>(
      H, H, st0, nullptr, nullptr, st1, tbl1,
      (const float*)d_in[8], (const float*)d_in[9],
      (const float*)d_in[10], (const float*)d_in[11],
      nullptr, nullptr, nullptr, nullptr, nullptr);

  layer_bt<16, false><<<dim3(NBT), blk, 0, stream>>>(
      H, H, st0, st1, nullptr, st2, tbl2,
      (const float*)d_in[15], (const float*)d_in[16],
      (const float*)d_in[17], (const float*)d_in[18],
      nullptr, nullptr, nullptr, nullptr, nullptr);

  layer_bt<24, true><<<dim3(NBT), blk, 0, stream>>>(
      H, nullptr, st0, st1, st2, nullptr, tbl3,
      (const float*)d_in[22], (const float*)d_in[23],
      (const float*)d_in[24], (const float*)d_in[25],
      (const float*)d_in[26], (const float*)d_in[27],
      (const float*)d_in[28], (const float*)d_in[29],
      out);
}

// Round 5
// 448.804 us; speedup vs baseline: 6.1370x; 1.1662x over previous
//
#include <hip/hip_runtime.h>
#include <hip/hip_fp16.h>

namespace {

constexpr int BATCH = 8;
constexpr int SLEN  = 262144;
constexpr int TT    = 1023;   // (262144-512)/256 + 1
constexpr int NF    = 257;    // rfft bins
constexpr int NCH   = 24;     // channels stored in H
constexpr int NBT   = BATCH * TT;   // 8184
constexpr int FRS   = NCH * NF;     // frame stride in halfs (6168)
constexpr float EPS = 1e-5f;

__device__ inline int div257(int e) { return (e * 65282) >> 24; }  // valid e<6168

// ---------------------------------------------------------------------------
// Kernel A: STFT (hann, 512-pt rfft) + l0 TD block. One workgroup per (b,t).
// DFT: per-lane 4-chain twiddle recurrence; ab[] reads wave-uniform.
// Writes H channels 0..7 (fp16) + LN partial stats st0 (fp32, from rounded).
// ---------------------------------------------------------------------------
__global__ __launch_bounds__(256) void stft_l0_kernel(
    const float* __restrict__ x,
    const float* __restrict__ W1g, const float* __restrict__ b1g,
    const float* __restrict__ W2g, const float* __restrict__ b2g,
    __half* __restrict__ H, float* __restrict__ stats0)
{
  __shared__ float  xw[512];     // windowed frame
  __shared__ float2 ab[256];     // {xw[n]+xw[512-n], xw[n]-xw[512-n]}, ab[0]=0
  __shared__ float  sre[NF + 2];
  __shared__ float  sim[NF + 2];
  __shared__ float  h1[4][NF + 2];
  __shared__ float  wW1[24], wb1[4], wW2[96], wb2[8];
  __shared__ float  red[8];

  const int tid = threadIdx.x;
  const int bt  = blockIdx.x;
  const int b   = bt / TT;
  const int t   = bt - b * TT;
  const float* xp = x + (size_t)b * SLEN + (size_t)t * 256;

  if (tid < 24) wW1[tid] = W1g[tid];
  if (tid < 4)  wb1[tid] = b1g[tid];
  if (tid < 96) wW2[tid] = W2g[tid];
  if (tid < 8)  wb2[tid] = b2g[tid];

  const float STEP = 6.283185307179586f / 512.0f;
  for (int n = tid; n < 512; n += 256) {
    float sv, cv;
    sincosf(STEP * (float)n, &sv, &cv);
    xw[n] = xp[n] * (0.5f - 0.5f * cv);   // hann window
  }
  __syncthreads();

  if (tid == 0) ab[0] = make_float2(0.f, 0.f);
  if (tid >= 1) {  // n = 1..255
    float u = xw[tid], v = xw[512 - tid];
    ab[tid] = make_float2(u + v, u - v);
  }
  __syncthreads();

  const float x0 = xw[0], x256 = xw[256];

  // ---- main DFT: lane k = tid (0..255), 4-chain twiddle recurrence ----
  {
    const int k = tid;
    float s1, c1;
    sincosf(STEP * (float)k, &s1, &c1);          // w = e^{i*theta}
    const float c2 = fmaf(c1, c1, -s1 * s1), s2 = 2.f * c1 * s1;         // w^2
    const float c3 = fmaf(c2, c1, -s2 * s1), s3 = fmaf(c2, s1, s2 * c1); // w^3
    const float c4 = fmaf(c2, c2, -s2 * s2), s4 = 2.f * c2 * s2;         // w^4
    float cA = 1.f, sA = 0.f;   // chain n = 4m
    float cB = c1,  sB = s1;    // chain n = 4m+1
    float cC = c2,  sC = s2;    // chain n = 4m+2
    float cD = c3,  sD = s3;    // chain n = 4m+3
    float re = x0 + ((k & 1) ? -x256 : x256);
    float im = 0.f;
    for (int m = 0; m < 64; ++m) {
      const float2 p0 = ab[4*m],     p1 = ab[4*m + 1];
      const float2 p2 = ab[4*m + 2], p3 = ab[4*m + 3];
      re = fmaf(p0.x, cA, re); im = fmaf(-p0.y, sA, im);
      re = fmaf(p1.x, cB, re); im = fmaf(-p1.y, sB, im);
      re = fmaf(p2.x, cC, re); im = fmaf(-p2.y, sC, im);
      re = fmaf(p3.x, cD, re); im = fmaf(-p3.y, sD, im);
      float t0;
      t0 = fmaf(cA, c4, -sA * s4); sA = fmaf(cA, s4, sA * c4); cA = t0;
      t0 = fmaf(cB, c4, -sB * s4); sB = fmaf(cB, s4, sB * c4); cB = t0;
      t0 = fmaf(cC, c4, -sC * s4); sC = fmaf(cC, s4, sC * c4); cC = t0;
      t0 = fmaf(cD, c4, -sD * s4); sD = fmaf(cD, s4, sD * c4); cD = t0;
    }
    sre[1 + k] = re;
    sim[1 + k] = im;
  }

  // ---- bin 256: re = x0 + x256 + sum (-1)^n ab[n].x ; im = 0 ----
  {
    float ps = 0.f;
    if (tid >= 1) ps = (tid & 1) ? -ab[tid].x : ab[tid].x;
    #pragma unroll
    for (int off = 32; off > 0; off >>= 1) ps += __shfl_down(ps, off, 64);
    if ((tid & 63) == 0) red[tid >> 6] = ps;
    __syncthreads();
    if (tid == 0) {
      sre[257] = x0 + x256 + red[0] + red[1] + red[2] + red[3];
      sim[257] = 0.f;
      sre[0] = 0.f; sim[0] = 0.f; sre[258] = 0.f; sim[258] = 0.f;
    }
  }
  __syncthreads();

  // conv1: (f,2) -> (f,4), k=3 same, relu
  for (int f = tid; f < NF; f += 256) {
    float acc[4] = {wb1[0], wb1[1], wb1[2], wb1[3]};
    #pragma unroll
    for (int i = 0; i < 3; ++i) {
      float vr = sre[f + i], vi = sim[f + i];
      #pragma unroll
      for (int c = 0; c < 4; ++c)
        acc[c] = fmaf(vr, wW1[(i*2+0)*4 + c], fmaf(vi, wW1[(i*2+1)*4 + c], acc[c]));
    }
    #pragma unroll
    for (int c = 0; c < 4; ++c) h1[c][f + 1] = fmaxf(acc[c], 0.f);
  }
  if (tid < 4) { h1[tid][0] = 0.f; h1[tid][NF + 1] = 0.f; }
  __syncthreads();

  // conv2: (f,4) -> (f,8), relu, store fp16 channel-major + stats (rounded)
  const size_t obase = (size_t)bt * FRS;
  float ps1 = 0.f, ps2 = 0.f;
  for (int f = tid; f < NF; f += 256) {
    float acc[8];
    #pragma unroll
    for (int c = 0; c < 8; ++c) acc[c] = wb2[c];
    #pragma unroll
    for (int i = 0; i < 3; ++i)
      #pragma unroll
      for (int c4 = 0; c4 < 4; ++c4) {
        float hv = h1[c4][f + i];
        #pragma unroll
        for (int c = 0; c < 8; ++c)
          acc[c] = fmaf(hv, wW2[(i*4+c4)*8 + c], acc[c]);
      }
    #pragma unroll
    for (int c = 0; c < 8; ++c) {
      const __half hv = __float2half(fmaxf(acc[c], 0.f));
      H[obase + (size_t)c * NF + f] = hv;
      const float v = __half2float(hv);
      ps1 += v;
      ps2 = fmaf(v, v, ps2);
    }
  }
  #pragma unroll
  for (int off = 32; off > 0; off >>= 1) {
    ps1 += __shfl_down(ps1, off, 64);
    ps2 += __shfl_down(ps2, off, 64);
  }
  if ((tid & 63) == 0) { red[(tid >> 6) * 2] = ps1; red[(tid >> 6) * 2 + 1] = ps2; }
  __syncthreads();
  if (tid == 0) {
    stats0[bt * 2]     = red[0] + red[2] + red[4] + red[6];
    stats0[bt * 2 + 1] = red[1] + red[3] + red[5] + red[7];
  }
}

// ---------------------------------------------------------------------------
// Fold LN/depthwise tables -> fp16 planes, channel-major [c][f]:
//   plane 0..2: P_dt = g*dw_dt     plane 3: Q0 = bn*(dw0+dw1+dw2)
//   plane 4:   Q1 = bn*(dw1+dw2)   plane 5: Q2 = bn*dw2
// ---------------------------------------------------------------------------
template<int CIN>
__global__ __launch_bounds__(256) void fold_tbl(
    const float* __restrict__ g, const float* __restrict__ bn,
    const float* __restrict__ dw, __half* __restrict__ dst)
{
  constexpr int NEL = CIN * NF;
  const int idx = blockIdx.x * 256 + threadIdx.x;
  if (idx >= NEL) return;
  const int c = div257(idx), f = idx - c * 257;
  const int s = f * CIN + c;
  const float gv = g[s], bv = bn[s];
  const float d0 = dw[s * 3], d1 = dw[s * 3 + 1], d2 = dw[s * 3 + 2];
  dst[idx]           = __float2half(gv * d0);
  dst[NEL + idx]     = __float2half(gv * d1);
  dst[2 * NEL + idx] = __float2half(gv * d2);
  dst[3 * NEL + idx] = __float2half(bv * (d0 + d1 + d2));
  dst[4 * NEL + idx] = __float2half(bv * (d1 + d2));
  dst[5 * NEL + idx] = __float2half(bv * d2);
}

// ---------------------------------------------------------------------------
// Layer kernel, one block per (b,t). LN stats from producer partials.
// Stage A: half2-pair loads of frames t-2..t + folded tables -> y in LDS.
// Stage B: conv1. Stage C: conv2 (+fp16 store+stats | head fc1/fc2/sigmoid).
// ---------------------------------------------------------------------------
template<int CIN, bool HEAD>
__global__ __launch_bounds__(256, 4) void layer_bt(
    const __half* __restrict__ H, __half* __restrict__ Hout,
    const float* __restrict__ st0, const float* __restrict__ st1,
    const float* __restrict__ st2, float* __restrict__ stats_out,
    const __half* __restrict__ tbl,
    const float* __restrict__ W1g, const float* __restrict__ b1g,
    const float* __restrict__ W2g, const float* __restrict__ b2g,
    const float* __restrict__ fc1W, const float* __restrict__ fc1b,
    const float* __restrict__ fc2W, const float* __restrict__ fc2b,
    float* __restrict__ out)
{
  constexpr int NEL   = CIN * NF;               // 2056 / 4112 / 6168
  constexpr int NP2   = NEL / 2;                // 1028 / 2056 / 3084
  constexpr int NPER2 = (NP2 + 255) / 256;      // 5 / 9 / 13
  constexpr int TAIL2 = NP2 - 256 * (NPER2 - 1);

  __shared__ float y[CIN * 259];     // depthwise out, padded rows (reused as out2)
  __shared__ float h1[8 * 259];      // conv1 out, padded rows
  __shared__ float wW1[3 * CIN * 8], wb1[8], wW2[192], wb2[8];
  __shared__ float red[8];
  __shared__ float wfc1[HEAD ? 96 : 1];

  const int tid = threadIdx.x;
  const int bt  = blockIdx.x;
  const int b   = bt / TT;
  const int t   = bt - b * TT;

  for (int i = tid; i < 3 * CIN * 8; i += 256) wW1[i] = W1g[i];
  if (tid < 192) wW2[tid] = W2g[tid];
  if (tid < 8) { wb1[tid] = b1g[tid]; wb2[tid] = b2g[tid]; }
  if (tid < CIN) { y[tid * 259] = 0.f; y[tid * 259 + 258] = 0.f; }
  if (tid < 8)   { h1[tid * 259] = 0.f; h1[tid * 259 + 258] = 0.f; }
  if constexpr (HEAD) { if (tid < 96) wfc1[tid] = fc1W[tid]; }

  // per-frame LN stats from producer partials (wave-uniform scalar loads)
  float mu0 = 0.f, rs0 = 0.f, mu1 = 0.f, rs1 = 0.f, mu2, rs2;
  {
    const float inv = 1.0f / (float)NEL;
    float s1 = st0[bt * 2], s2v = st0[bt * 2 + 1];
    if constexpr (CIN >= 16) { s1 += st1[bt * 2]; s2v += st1[bt * 2 + 1]; }
    if constexpr (CIN >= 24) { s1 += st2[bt * 2]; s2v += st2[bt * 2 + 1]; }
    mu2 = s1 * inv; rs2 = rsqrtf(s2v * inv - mu2 * mu2 + EPS);
    if (t >= 1) {
      const int fb = bt - 1;
      float a = st0[fb * 2], c = st0[fb * 2 + 1];
      if constexpr (CIN >= 16) { a += st1[fb * 2]; c += st1[fb * 2 + 1]; }
      if constexpr (CIN >= 24) { a += st2[fb * 2]; c += st2[fb * 2 + 1]; }
      mu1 = a * inv; rs1 = rsqrtf(c * inv - mu1 * mu1 + EPS);
    }
    if (t >= 2) {
      const int fb = bt - 2;
      float a = st0[fb * 2], c = st0[fb * 2 + 1];
      if constexpr (CIN >= 16) { a += st1[fb * 2]; c += st1[fb * 2 + 1]; }
      if constexpr (CIN >= 24) { a += st2[fb * 2]; c += st2[fb * 2 + 1]; }
      mu0 = a * inv; rs0 = rsqrtf(c * inv - mu0 * mu0 + EPS);
    }
  }

  // clamped frame pointers (missing frames: rs=0 kills the contribution)
  const int base = b * TT;
  const __half2* f2p = (const __half2*)(H + (size_t)bt * FRS);
  const __half2* f1p = (const __half2*)(H + (size_t)max(bt - 1, base) * FRS);
  const __half2* f0p = (const __half2*)(H + (size_t)max(bt - 2, base) * FRS);
  const __half2* P0p = (const __half2*)tbl;
  const __half2* P1p = (const __half2*)(tbl + NEL);
  const __half2* P2p = (const __half2*)(tbl + 2 * NEL);
  const int qsel = (t >= 2) ? 0 : (t == 1 ? 1 : 2);
  const __half2* Qp  = (const __half2*)(tbl + (3 + qsel) * NEL);

  // ---- stage A: LN + causal depthwise into y (half2 pairs) ----
  #pragma unroll
  for (int j = 0; j < NPER2; ++j) {
    const bool act = (j < NPER2 - 1) || (tid < TAIL2);
    if (act) {
      const int p  = tid + 256 * j;
      const int e0 = 2 * p;
      const int c0 = div257(e0);
      const int fi = e0 - c0 * 257;
      const float2 xa = __half22float2(f0p[p]);
      const float2 xb = __half22float2(f1p[p]);
      const float2 xc = __half22float2(f2p[p]);
      const float2 pa = __half22float2(P0p[p]);
      const float2 pb = __half22float2(P1p[p]);
      const float2 pc = __half22float2(P2p[p]);
      const float2 qq = __half22float2(Qp[p]);
      const float y0 = fmaf((xa.x - mu0) * rs0, pa.x,
                       fmaf((xb.x - mu1) * rs1, pb.x,
                       fmaf((xc.x - mu2) * rs2, pc.x, qq.x)));
      const float y1 = fmaf((xa.y - mu0) * rs0, pa.y,
                       fmaf((xb.y - mu1) * rs1, pb.y,
                       fmaf((xc.y - mu2) * rs2, pc.y, qq.y)));
      const int a0 = c0 * 259 + 1 + fi;
      y[a0] = y0;
      y[a0 + ((fi == 256) ? 3 : 1)] = y1;   // next elem may start a new row
    }
  }
  __syncthreads();

  // ---- stage B: conv1 (f,CIN)->(f,8), k=3 same, relu ----
  {
    const int f = tid;  // 0..255
    float acc[8];
    #pragma unroll
    for (int c = 0; c < 8; ++c) acc[c] = wb1[c];
    #pragma unroll
    for (int i = 0; i < 3; ++i)
      for (int cin = 0; cin < CIN; ++cin) {
        const float yv = y[cin * 259 + f + i];
        #pragma unroll
        for (int c = 0; c < 8; ++c)
          acc[c] = fmaf(yv, wW1[(i * CIN + cin) * 8 + c], acc[c]);
      }
    #pragma unroll
    for (int c = 0; c < 8; ++c) h1[c * 259 + 1 + f] = fmaxf(acc[c], 0.f);
  }
  if (tid < 8) {  // sidecar: bin 256, out-channel = tid
    float a = wb1[tid];
    #pragma unroll
    for (int i = 0; i < 3; ++i)
      for (int cin = 0; cin < CIN; ++cin)
        a = fmaf(y[cin * 259 + 256 + i], wW1[(i * CIN + cin) * 8 + tid], a);
    h1[tid * 259 + 257] = fmaxf(a, 0.f);
  }
  __syncthreads();

  // ---- stage C: conv2 (f,8)->(f,8), k=3 same, relu ----
  float* out2 = y;  // y dead after conv1; reuse as out2[c*257+f] (HEAD)
  float ps1 = 0.f, ps2 = 0.f;
  {
    const int f = tid;
    float o2[8];
    #pragma unroll
    for (int c = 0; c < 8; ++c) o2[c] = wb2[c];
    #pragma unroll
    for (int i = 0; i < 3; ++i)
      #pragma unroll
      for (int c8 = 0; c8 < 8; ++c8) {
        const float hv = h1[c8 * 259 + f + i];
        #pragma unroll
        for (int c = 0; c < 8; ++c)
          o2[c] = fmaf(hv, wW2[(i * 8 + c8) * 8 + c], o2[c]);
      }
    if constexpr (!HEAD) {
      const size_t ob = (size_t)bt * FRS + (size_t)CIN * NF;
      #pragma unroll
      for (int c = 0; c < 8; ++c) {
        const __half hv = __float2half(fmaxf(o2[c], 0.f));
        Hout[ob + (size_t)c * NF + f] = hv;
        const float v = __half2float(hv);
        ps1 += v;
        ps2 = fmaf(v, v, ps2);
      }
    } else {
      #pragma unroll
      for (int c = 0; c < 8; ++c) out2[c * 257 + f] = fmaxf(o2[c], 0.f);
    }
  }
  if (tid >= 8 && tid < 16) {  // sidecar: bin 256, ch = tid-8
    const int c8 = tid - 8;
    float a = wb2[c8];
    #pragma unroll
    for (int i = 0; i < 3; ++i)
      #pragma unroll
      for (int cp = 0; cp < 8; ++cp)
        a = fmaf(h1[cp * 259 + 256 + i], wW2[(i * 8 + cp) * 8 + c8], a);
    if constexpr (!HEAD) {
      const size_t ob = (size_t)bt * FRS + (size_t)CIN * NF;
      const __half hv = __float2half(fmaxf(a, 0.f));
      Hout[ob + (size_t)c8 * NF + 256] = hv;
      const float v = __half2float(hv);
      ps1 += v;
      ps2 = fmaf(v, v, ps2);
    } else {
      out2[c8 * 257 + 256] = fmaxf(a, 0.f);
    }
  }

  if constexpr (!HEAD) {
    #pragma unroll
    for (int off = 32; off > 0; off >>= 1) {
      ps1 += __shfl_down(ps1, off, 64);
      ps2 += __shfl_down(ps2, off, 64);
    }
    if ((tid & 63) == 0) { red[(tid >> 6) * 2] = ps1; red[(tid >> 6) * 2 + 1] = ps2; }
    __syncthreads();
    if (tid == 0) {
      stats_out[bt * 2]     = red[0] + red[2] + red[4] + red[6];
      stats_out[bt * 2 + 1] = red[1] + red[3] + red[5] + red[7];
    }
  } else {
    __syncthreads();  // out2 complete
    // ---- stage D: fc1 (valid k=3, 32ch) + relu + fc2 + sigmoid ----
    float part = 0.f;
    if (tid < NF - 2) {
      const __half* xg = (const __half*)f2p;  // raw frame t, L1-warm
      float acc = fc1b[0];
      #pragma unroll
      for (int i = 0; i < 3; ++i) {
        for (int c = 0; c < 24; ++c)
          acc = fmaf(__half2float(xg[c * 257 + tid + i]), wfc1[i * 32 + c], acc);
        #pragma unroll
        for (int c8 = 0; c8 < 8; ++c8)
          acc = fmaf(out2[c8 * 257 + tid + i], wfc1[i * 32 + 24 + c8], acc);
      }
      part = fmaxf(acc, 0.f) * fc2W[tid];
    }
    #pragma unroll
    for (int off = 32; off > 0; off >>= 1) part += __shfl_down(part, off, 64);
    if ((tid & 63) == 0) red[tid >> 6] = part;
    __syncthreads();
    if (tid == 0) {
      const float tot = red[0] + red[1] + red[2] + red[3] + fc2b[0];
      out[bt] = 1.0f / (1.0f + expf(-tot));
    }
  }
}

}  // namespace

extern "C" void kernel_launch(void* const* d_in, const int* in_sizes, int n_in,
                              void* d_out, int out_size, void* d_ws, size_t ws_size,
                              hipStream_t stream) {
  (void)in_sizes; (void)n_in; (void)out_size; (void)ws_size;
  const float* x = (const float*)d_in[0];
  float* out = (float*)d_out;
  char*  wsb = (char*)d_ws;

  // Workspace layout (bytes)
  __half* H   = (__half*)wsb;                       // NBT*FRS halfs = ~101 MB
  char* p = wsb + (size_t)NBT * FRS * sizeof(__half);
  float* st0  = (float*)p; p += 2 * NBT * sizeof(float);
  float* st1  = (float*)p; p += 2 * NBT * sizeof(float);
  float* st2  = (float*)p; p += 2 * NBT * sizeof(float);
  __half* tbl1 = (__half*)p; p += 6 * (8  * NF) * sizeof(__half);
  __half* tbl2 = (__half*)p; p += 6 * (16 * NF) * sizeof(__half);
  __half* tbl3 = (__half*)p;

  dim3 blk(256);

  fold_tbl<8><<<dim3((8 * NF + 255) / 256), blk, 0, stream>>>(
      (const float*)d_in[5], (const float*)d_in[6], (const float*)d_in[7], tbl1);
  fold_tbl<16><<<dim3((16 * NF + 255) / 256), blk, 0, stream>>>(
      (const float*)d_in[12], (const float*)d_in[13], (const float*)d_in[14], tbl2);
  fold_tbl<24><<<dim3((24 * NF + 255) / 256), blk, 0, stream>>>(
      (const float*)d_in[19], (const float*)d_in[20], (const float*)d_in[21], tbl3);

  stft_l0_kernel<<<dim3(NBT), blk, 0, stream>>>(
      x, (const float*)d_in[1], (const float*)d_in[2],
      (const float*)d_in[3], (const float*)d_in[4], H, st0);

  layer_bt<8, false><<<dim3(NBT), blk, 0, stream>>>(
      H, H, st0, nullptr, nullptr, st1, tbl1,
      (const float*)d_in[8], (const float*)d_in[9],
      (const float*)d_in[10], (const float*)d_in[11],
      nullptr, nullptr, nullptr, nullptr, nullptr);

  layer_bt<16, false><<<dim3(NBT), blk, 0, stream>>>(
      H, H, st0, st1, nullptr, st2, tbl2,
      (const float*)d_in[15], (const float*)d_in[16],
      (const float*)d_in[17], (const float*)d_in[18],
      nullptr, nullptr, nullptr, nullptr, nullptr);

  layer_bt<24, true><<<dim3(NBT), blk, 0, stream>>>(
      H, nullptr, st0, st1, st2, nullptr, tbl3,
      (const float*)d_in[22], (const float*)d_in[23],
      (const float*)d_in[24], (const float*)d_in[25],
      (const float*)d_in[26], (const float*)d_in[27],
      (const float*)d_in[28], (const float*)d_in[29],
      out);
}

// Round 6
// 442.321 us; speedup vs baseline: 6.2270x; 1.0147x over previous
//
#include <hip/hip_runtime.h>
#include <hip/hip_fp16.h>

namespace {

constexpr int BATCH = 8;
constexpr int SLEN  = 262144;
constexpr int TT    = 1023;   // (262144-512)/256 + 1
constexpr int NF    = 257;    // rfft bins
constexpr int NCH   = 24;     // channels stored in H
constexpr int NBT   = BATCH * TT;   // 8184
constexpr int FRS   = NCH * NF;     // frame stride in halfs (6168)
constexpr float EPS = 1e-5f;

__device__ inline int div257(int e) { return (e * 65282) >> 24; }  // valid e<6168

// ---------------------------------------------------------------------------
// Kernel A: STFT (hann, 512-pt rfft) + l0 TD block. One workgroup per (b,t).
// DFT: lanes 0..127 compute bin-pair (k, 256-k) via even/odd-n accumulators
// (cos/sin parity symmetry) with 4-chain twiddle recurrence; bin 128 via
// alternating reduction on lanes 128..255. Exact math vs naive DFT.
// Writes H channels 0..7 (fp16) + LN partial stats st0.
// ---------------------------------------------------------------------------
__global__ __launch_bounds__(256, 8) void stft_l0_kernel(
    const float* __restrict__ x,
    const float* __restrict__ W1g, const float* __restrict__ b1g,
    const float* __restrict__ W2g, const float* __restrict__ b2g,
    __half* __restrict__ H, float* __restrict__ stats0)
{
  __shared__ float  xw[512];     // windowed frame
  __shared__ __align__(16) float2 ab[256];  // {x[n]+x[512-n], x[n]-x[512-n]}
  __shared__ float  sre[NF + 2];
  __shared__ float  sim[NF + 2];
  __shared__ float  h1[4][NF + 2];
  __shared__ float  wW1[24], wb1[4], wW2[96], wb2[8];
  __shared__ float  red[8];

  const int tid = threadIdx.x;
  const int bt  = blockIdx.x;
  const int b   = bt / TT;
  const int t   = bt - b * TT;
  const float* xp = x + (size_t)b * SLEN + (size_t)t * 256;

  if (tid < 24) wW1[tid] = W1g[tid];
  if (tid < 4)  wb1[tid] = b1g[tid];
  if (tid < 96) wW2[tid] = W2g[tid];
  if (tid < 8)  wb2[tid] = b2g[tid];

  const float STEP = 6.283185307179586f / 512.0f;
  for (int n = tid; n < 512; n += 256) {
    float sv, cv;
    sincosf(STEP * (float)n, &sv, &cv);
    xw[n] = xp[n] * (0.5f - 0.5f * cv);   // hann window
  }
  __syncthreads();

  if (tid == 0) ab[0] = make_float2(0.f, 0.f);
  if (tid >= 1) {  // n = 1..255
    float u = xw[tid], v = xw[512 - tid];
    ab[tid] = make_float2(u + v, u - v);
  }
  __syncthreads();

  const float x0 = xw[0], x256 = xw[256];

  if (tid < 128) {
    // ---- DFT bin-pair (k, 256-k), k = tid: even/odd-n accumulators ----
    const int k = tid;
    float s1, c1;
    sincosf(STEP * (float)k, &s1, &c1);          // w = e^{i*theta}
    const float c2 = fmaf(c1, c1, -s1 * s1), s2 = 2.f * c1 * s1;         // w^2
    const float c3 = fmaf(c2, c1, -s2 * s1), s3 = fmaf(c2, s1, s2 * c1); // w^3
    const float c4 = fmaf(c2, c2, -s2 * s2), s4 = 2.f * c2 * s2;         // w^4
    float cA = 1.f, sA = 0.f;   // chain n = 4m   (even)
    float cB = c1,  sB = s1;    // chain n = 4m+1 (odd)
    float cC = c2,  sC = s2;    // chain n = 4m+2 (even)
    float cD = c3,  sD = s3;    // chain n = 4m+3 (odd)
    float re_e = 0.f, re_o = 0.f, im_e = 0.f, im_o = 0.f;
    const float4* ab4 = (const float4*)ab;
    for (int m = 0; m < 64; ++m) {
      const float4 q0 = ab4[2 * m];       // {ab[4m].x, ab[4m].y, ab[4m+1].x, ab[4m+1].y}
      const float4 q1 = ab4[2 * m + 1];   // {ab[4m+2].x, .y, ab[4m+3].x, .y}
      re_e = fmaf(q0.x, cA, re_e); im_e = fmaf(q0.y, sA, im_e);
      re_o = fmaf(q0.z, cB, re_o); im_o = fmaf(q0.w, sB, im_o);
      re_e = fmaf(q1.x, cC, re_e); im_e = fmaf(q1.y, sC, im_e);
      re_o = fmaf(q1.z, cD, re_o); im_o = fmaf(q1.w, sD, im_o);
      float t0;
      t0 = fmaf(cA, c4, -sA * s4); sA = fmaf(cA, s4, sA * c4); cA = t0;
      t0 = fmaf(cB, c4, -sB * s4); sB = fmaf(cB, s4, sB * c4); cB = t0;
      t0 = fmaf(cC, c4, -sC * s4); sC = fmaf(cC, s4, sC * c4); cC = t0;
      t0 = fmaf(cD, c4, -sD * s4); sD = fmaf(cD, s4, sD * c4); cD = t0;
    }
    const float rb = x0 + ((k & 1) ? -x256 : x256);
    sre[1 + k] = rb + re_e + re_o;          // bin k
    sim[1 + k] = -(im_e + im_o);
    sre[1 + 256 - k] = rb + re_e - re_o;    // bin 256-k (k=0 -> bin 256)
    sim[1 + 256 - k] = im_e - im_o;
  } else {
    // ---- bin 128 terms on lanes 128..255: m = tid-128 ----
    const int m = tid - 128;
    const float sgn = (m & 1) ? -1.f : 1.f;
    float tr = ab[2 * m].x * sgn;           // re128 term (n = 2m even)
    float ti = -ab[2 * m + 1].y * sgn;      // im128 term (n = 2m+1 odd)
    #pragma unroll
    for (int off = 32; off > 0; off >>= 1) {
      tr += __shfl_down(tr, off, 64);
      ti += __shfl_down(ti, off, 64);
    }
    if ((tid & 63) == 0) {
      const int w = (tid >> 6) - 2;  // 0 or 1
      red[w * 2] = tr; red[w * 2 + 1] = ti;
    }
  }
  __syncthreads();
  if (tid == 0) {
    sre[1 + 128] = x0 + x256 + red[0] + red[2];
    sim[1 + 128] = red[1] + red[3];
    sre[0] = 0.f; sim[0] = 0.f; sre[258] = 0.f; sim[258] = 0.f;
  }
  __syncthreads();

  // conv1: (f,2) -> (f,4), k=3 same, relu
  for (int f = tid; f < NF; f += 256) {
    float acc[4] = {wb1[0], wb1[1], wb1[2], wb1[3]};
    #pragma unroll
    for (int i = 0; i < 3; ++i) {
      float vr = sre[f + i], vi = sim[f + i];
      #pragma unroll
      for (int c = 0; c < 4; ++c)
        acc[c] = fmaf(vr, wW1[(i*2+0)*4 + c], fmaf(vi, wW1[(i*2+1)*4 + c], acc[c]));
    }
    #pragma unroll
    for (int c = 0; c < 4; ++c) h1[c][f + 1] = fmaxf(acc[c], 0.f);
  }
  if (tid < 4) { h1[tid][0] = 0.f; h1[tid][NF + 1] = 0.f; }
  __syncthreads();

  // conv2: (f,4) -> (f,8), relu, store fp16 channel-major + stats (rounded)
  const size_t obase = (size_t)bt * FRS;
  float ps1 = 0.f, ps2 = 0.f;
  for (int f = tid; f < NF; f += 256) {
    float acc[8];
    #pragma unroll
    for (int c = 0; c < 8; ++c) acc[c] = wb2[c];
    #pragma unroll
    for (int i = 0; i < 3; ++i)
      #pragma unroll
      for (int c4 = 0; c4 < 4; ++c4) {
        float hv = h1[c4][f + i];
        #pragma unroll
        for (int c = 0; c < 8; ++c)
          acc[c] = fmaf(hv, wW2[(i*4+c4)*8 + c], acc[c]);
      }
    #pragma unroll
    for (int c = 0; c < 8; ++c) {
      const __half hv = __float2half(fmaxf(acc[c], 0.f));
      H[obase + (size_t)c * NF + f] = hv;
      const float v = __half2float(hv);
      ps1 += v;
      ps2 = fmaf(v, v, ps2);
    }
  }
  #pragma unroll
  for (int off = 32; off > 0; off >>= 1) {
    ps1 += __shfl_down(ps1, off, 64);
    ps2 += __shfl_down(ps2, off, 64);
  }
  if ((tid & 63) == 0) { red[(tid >> 6) * 2] = ps1; red[(tid >> 6) * 2 + 1] = ps2; }
  __syncthreads();
  if (tid == 0) {
    stats0[bt * 2]     = red[0] + red[2] + red[4] + red[6];
    stats0[bt * 2 + 1] = red[1] + red[3] + red[5] + red[7];
  }
}

// ---------------------------------------------------------------------------
// Fold LN/depthwise tables -> fp16 planes, channel-major [c][f]:
//   plane 0..2: P_dt = g*dw_dt     plane 3: Q0 = bn*(dw0+dw1+dw2)
//   plane 4:   Q1 = bn*(dw1+dw2)   plane 5: Q2 = bn*dw2
// ---------------------------------------------------------------------------
template<int CIN>
__global__ __launch_bounds__(256) void fold_tbl(
    const float* __restrict__ g, const float* __restrict__ bn,
    const float* __restrict__ dw, __half* __restrict__ dst)
{
  constexpr int NEL = CIN * NF;
  const int idx = blockIdx.x * 256 + threadIdx.x;
  if (idx >= NEL) return;
  const int c = div257(idx), f = idx - c * 257;
  const int s = f * CIN + c;
  const float gv = g[s], bv = bn[s];
  const float d0 = dw[s * 3], d1 = dw[s * 3 + 1], d2 = dw[s * 3 + 2];
  dst[idx]           = __float2half(gv * d0);
  dst[NEL + idx]     = __float2half(gv * d1);
  dst[2 * NEL + idx] = __float2half(gv * d2);
  dst[3 * NEL + idx] = __float2half(bv * (d0 + d1 + d2));
  dst[4 * NEL + idx] = __float2half(bv * (d1 + d2));
  dst[5 * NEL + idx] = __float2half(bv * d2);
}

// ---------------------------------------------------------------------------
// Layer kernel, one block per (b,t). LN stats from producer partials.
// fp16 LDS for y/h1/out2 -> ~20 KB -> 8 blocks/CU (wave cap).
// ---------------------------------------------------------------------------
template<int CIN, bool HEAD>
__global__ __launch_bounds__(256, 8) void layer_bt(
    const __half* __restrict__ H, __half* __restrict__ Hout,
    const float* __restrict__ st0, const float* __restrict__ st1,
    const float* __restrict__ st2, float* __restrict__ stats_out,
    const __half* __restrict__ tbl,
    const float* __restrict__ W1g, const float* __restrict__ b1g,
    const float* __restrict__ W2g, const float* __restrict__ b2g,
    const float* __restrict__ fc1W, const float* __restrict__ fc1b,
    const float* __restrict__ fc2W, const float* __restrict__ fc2b,
    float* __restrict__ out)
{
  constexpr int NEL   = CIN * NF;               // 2056 / 4112 / 6168
  constexpr int NP2   = NEL / 2;                // 1028 / 2056 / 3084
  constexpr int NPER2 = (NP2 + 255) / 256;      // 5 / 9 / 13
  constexpr int TAIL2 = NP2 - 256 * (NPER2 - 1);

  __shared__ __half y[CIN * 259];    // depthwise out, padded rows (reused as out2)
  __shared__ __half h1[8 * 259];     // conv1 out, padded rows
  __shared__ float wW1[3 * CIN * 8], wb1[8], wW2[192], wb2[8];
  __shared__ float red[8];
  __shared__ float wfc1[HEAD ? 96 : 1];

  const int tid = threadIdx.x;
  const int bt  = blockIdx.x;
  const int b   = bt / TT;
  const int t   = bt - b * TT;

  const __half hz = __float2half(0.f);
  for (int i = tid; i < 3 * CIN * 8; i += 256) wW1[i] = W1g[i];
  if (tid < 192) wW2[tid] = W2g[tid];
  if (tid < 8) { wb1[tid] = b1g[tid]; wb2[tid] = b2g[tid]; }
  if (tid < CIN) { y[tid * 259] = hz; y[tid * 259 + 258] = hz; }
  if (tid < 8)   { h1[tid * 259] = hz; h1[tid * 259 + 258] = hz; }
  if constexpr (HEAD) { if (tid < 96) wfc1[tid] = fc1W[tid]; }

  // per-frame LN stats from producer partials (wave-uniform scalar loads)
  float mu0 = 0.f, rs0 = 0.f, mu1 = 0.f, rs1 = 0.f, mu2, rs2;
  {
    const float inv = 1.0f / (float)NEL;
    float s1 = st0[bt * 2], s2v = st0[bt * 2 + 1];
    if constexpr (CIN >= 16) { s1 += st1[bt * 2]; s2v += st1[bt * 2 + 1]; }
    if constexpr (CIN >= 24) { s1 += st2[bt * 2]; s2v += st2[bt * 2 + 1]; }
    mu2 = s1 * inv; rs2 = rsqrtf(s2v * inv - mu2 * mu2 + EPS);
    if (t >= 1) {
      const int fb = bt - 1;
      float a = st0[fb * 2], c = st0[fb * 2 + 1];
      if constexpr (CIN >= 16) { a += st1[fb * 2]; c += st1[fb * 2 + 1]; }
      if constexpr (CIN >= 24) { a += st2[fb * 2]; c += st2[fb * 2 + 1]; }
      mu1 = a * inv; rs1 = rsqrtf(c * inv - mu1 * mu1 + EPS);
    }
    if (t >= 2) {
      const int fb = bt - 2;
      float a = st0[fb * 2], c = st0[fb * 2 + 1];
      if constexpr (CIN >= 16) { a += st1[fb * 2]; c += st1[fb * 2 + 1]; }
      if constexpr (CIN >= 24) { a += st2[fb * 2]; c += st2[fb * 2 + 1]; }
      mu0 = a * inv; rs0 = rsqrtf(c * inv - mu0 * mu0 + EPS);
    }
  }

  // clamped frame pointers (missing frames: rs=0 kills the contribution)
  const int base = b * TT;
  const __half2* f2p = (const __half2*)(H + (size_t)bt * FRS);
  const __half2* f1p = (const __half2*)(H + (size_t)max(bt - 1, base) * FRS);
  const __half2* f0p = (const __half2*)(H + (size_t)max(bt - 2, base) * FRS);
  const __half2* P0p = (const __half2*)tbl;
  const __half2* P1p = (const __half2*)(tbl + NEL);
  const __half2* P2p = (const __half2*)(tbl + 2 * NEL);
  const int qsel = (t >= 2) ? 0 : (t == 1 ? 1 : 2);
  const __half2* Qp  = (const __half2*)(tbl + (3 + qsel) * NEL);

  // ---- stage A: LN + causal depthwise into y (half2 pair loads) ----
  #pragma unroll
  for (int j = 0; j < NPER2; ++j) {
    const bool act = (j < NPER2 - 1) || (tid < TAIL2);
    if (act) {
      const int p  = tid + 256 * j;
      const int e0 = 2 * p;
      const int c0 = div257(e0);
      const int fi = e0 - c0 * 257;
      const float2 xa = __half22float2(f0p[p]);
      const float2 xb = __half22float2(f1p[p]);
      const float2 xc = __half22float2(f2p[p]);
      const float2 pa = __half22float2(P0p[p]);
      const float2 pb = __half22float2(P1p[p]);
      const float2 pc = __half22float2(P2p[p]);
      const float2 qq = __half22float2(Qp[p]);
      const float y0 = fmaf((xa.x - mu0) * rs0, pa.x,
                       fmaf((xb.x - mu1) * rs1, pb.x,
                       fmaf((xc.x - mu2) * rs2, pc.x, qq.x)));
      const float y1 = fmaf((xa.y - mu0) * rs0, pa.y,
                       fmaf((xb.y - mu1) * rs1, pb.y,
                       fmaf((xc.y - mu2) * rs2, pc.y, qq.y)));
      const int a0 = c0 * 259 + 1 + fi;
      y[a0] = __float2half(y0);
      y[a0 + ((fi == 256) ? 3 : 1)] = __float2half(y1);  // may start a new row
    }
  }
  __syncthreads();

  // ---- stage B: conv1 (f,CIN)->(f,8), k=3 same, relu ----
  {
    const int f = tid;  // 0..255
    float acc[8];
    #pragma unroll
    for (int c = 0; c < 8; ++c) acc[c] = wb1[c];
    #pragma unroll
    for (int i = 0; i < 3; ++i)
      for (int cin = 0; cin < CIN; ++cin) {
        const float yv = __half2float(y[cin * 259 + f + i]);
        #pragma unroll
        for (int c = 0; c < 8; ++c)
          acc[c] = fmaf(yv, wW1[(i * CIN + cin) * 8 + c], acc[c]);
      }
    #pragma unroll
    for (int c = 0; c < 8; ++c)
      h1[c * 259 + 1 + f] = __float2half(fmaxf(acc[c], 0.f));
  }
  if (tid < 8) {  // sidecar: bin 256, out-channel = tid
    float a = wb1[tid];
    #pragma unroll
    for (int i = 0; i < 3; ++i)
      for (int cin = 0; cin < CIN; ++cin)
        a = fmaf(__half2float(y[cin * 259 + 256 + i]), wW1[(i * CIN + cin) * 8 + tid], a);
    h1[tid * 259 + 257] = __float2half(fmaxf(a, 0.f));
  }
  __syncthreads();

  // ---- stage C: conv2 (f,8)->(f,8), k=3 same, relu ----
  __half* out2 = y;  // y dead after conv1; reuse as out2[c*257+f] (HEAD)
  float ps1 = 0.f, ps2 = 0.f;
  {
    const int f = tid;
    float o2[8];
    #pragma unroll
    for (int c = 0; c < 8; ++c) o2[c] = wb2[c];
    #pragma unroll
    for (int i = 0; i < 3; ++i)
      #pragma unroll
      for (int c8 = 0; c8 < 8; ++c8) {
        const float hv = __half2float(h1[c8 * 259 + f + i]);
        #pragma unroll
        for (int c = 0; c < 8; ++c)
          o2[c] = fmaf(hv, wW2[(i * 8 + c8) * 8 + c], o2[c]);
      }
    if constexpr (!HEAD) {
      const size_t ob = (size_t)bt * FRS + (size_t)CIN * NF;
      #pragma unroll
      for (int c = 0; c < 8; ++c) {
        const __half hv = __float2half(fmaxf(o2[c], 0.f));
        Hout[ob + (size_t)c * NF + f] = hv;
        const float v = __half2float(hv);
        ps1 += v;
        ps2 = fmaf(v, v, ps2);
      }
    } else {
      #pragma unroll
      for (int c = 0; c < 8; ++c)
        out2[c * 257 + f] = __float2half(fmaxf(o2[c], 0.f));
    }
  }
  if (tid >= 8 && tid < 16) {  // sidecar: bin 256, ch = tid-8
    const int c8 = tid - 8;
    float a = wb2[c8];
    #pragma unroll
    for (int i = 0; i < 3; ++i)
      #pragma unroll
      for (int cp = 0; cp < 8; ++cp)
        a = fmaf(__half2float(h1[cp * 259 + 256 + i]), wW2[(i * 8 + cp) * 8 + c8], a);
    if constexpr (!HEAD) {
      const size_t ob = (size_t)bt * FRS + (size_t)CIN * NF;
      const __half hv = __float2half(fmaxf(a, 0.f));
      Hout[ob + (size_t)c8 * NF + 256] = hv;
      const float v = __half2float(hv);
      ps1 += v;
      ps2 = fmaf(v, v, ps2);
    } else {
      out2[c8 * 257 + 256] = __float2half(fmaxf(a, 0.f));
    }
  }

  if constexpr (!HEAD) {
    #pragma unroll
    for (int off = 32; off > 0; off >>= 1) {
      ps1 += __shfl_down(ps1, off, 64);
      ps2 += __shfl_down(ps2, off, 64);
    }
    if ((tid & 63) == 0) { red[(tid >> 6) * 2] = ps1; red[(tid >> 6) * 2 + 1] = ps2; }
    __syncthreads();
    if (tid == 0) {
      stats_out[bt * 2]     = red[0] + red[2] + red[4] + red[6];
      stats_out[bt * 2 + 1] = red[1] + red[3] + red[5] + red[7];
    }
  } else {
    __syncthreads();  // out2 complete
    // ---- stage D: fc1 (valid k=3, 32ch) + relu + fc2 + sigmoid ----
    float part = 0.f;
    if (tid < NF - 2) {
      const __half* xg = (const __half*)f2p;  // raw frame t, L1-warm
      float acc = fc1b[0];
      #pragma unroll
      for (int i = 0; i < 3; ++i) {
        for (int c = 0; c < 24; ++c)
          acc = fmaf(__half2float(xg[c * 257 + tid + i]), wfc1[i * 32 + c], acc);
        #pragma unroll
        for (int c8 = 0; c8 < 8; ++c8)
          acc = fmaf(__half2float(out2[c8 * 257 + tid + i]), wfc1[i * 32 + 24 + c8], acc);
      }
      part = fmaxf(acc, 0.f) * fc2W[tid];
    }
    #pragma unroll
    for (int off = 32; off > 0; off >>= 1) part += __shfl_down(part, off, 64);
    if ((tid & 63) == 0) red[tid >> 6] = part;
    __syncthreads();
    if (tid == 0) {
      const float tot = red[0] + red[1] + red[2] + red[3] + fc2b[0];
      out[bt] = 1.0f / (1.0f + expf(-tot));
    }
  }
}

}  // namespace

extern "C" void kernel_launch(void* const* d_in, const int* in_sizes, int n_in,
                              void* d_out, int out_size, void* d_ws, size_t ws_size,
                              hipStream_t stream) {
  (void)in_sizes; (void)n_in; (void)out_size; (void)ws_size;
  const float* x = (const float*)d_in[0];
  float* out = (float*)d_out;
  char*  wsb = (char*)d_ws;

  // Workspace layout (bytes)
  __half* H   = (__half*)wsb;                       // NBT*FRS halfs = ~101 MB
  char* p = wsb + (size_t)NBT * FRS * sizeof(__half);
  float* st0  = (float*)p; p += 2 * NBT * sizeof(float);
  float* st1  = (float*)p; p += 2 * NBT * sizeof(float);
  float* st2  = (float*)p; p += 2 * NBT * sizeof(float);
  __half* tbl1 = (__half*)p; p += 6 * (8  * NF) * sizeof(__half);
  __half* tbl2 = (__half*)p; p += 6 * (16 * NF) * sizeof(__half);
  __half* tbl3 = (__half*)p;

  dim3 blk(256);

  fold_tbl<8><<<dim3((8 * NF + 255) / 256), blk, 0, stream>>>(
      (const float*)d_in[5], (const float*)d_in[6], (const float*)d_in[7], tbl1);
  fold_tbl<16><<<dim3((16 * NF + 255) / 256), blk, 0, stream>>>(
      (const float*)d_in[12], (const float*)d_in[13], (const float*)d_in[14], tbl2);
  fold_tbl<24><<<dim3((24 * NF + 255) / 256), blk, 0, stream>>>(
      (const float*)d_in[19], (const float*)d_in[20], (const float*)d_in[21], tbl3);

  stft_l0_kernel<<<dim3(NBT), blk, 0, stream>>>(
      x, (const float*)d_in[1], (const float*)d_in[2],
      (const float*)d_in[3], (const float*)d_in[4], H, st0);

  layer_bt<8, false><<<dim3(NBT), blk, 0, stream>>>(
      H, H, st0, nullptr, nullptr, st1, tbl1,
      (const float*)d_in[8], (const float*)d_in[9],
      (const float*)d_in[10], (const float*)d_in[11],
      nullptr, nullptr, nullptr, nullptr, nullptr);

  layer_bt<16, false><<<dim3(NBT), blk, 0, stream>>>(
      H, H, st0, st1, nullptr, st2, tbl2,
      (const float*)d_in[15], (const float*)d_in[16],
      (const float*)d_in[17], (const float*)d_in[18],
      nullptr, nullptr, nullptr, nullptr, nullptr);

  layer_bt<24, true><<<dim3(NBT), blk, 0, stream>>>(
      H, nullptr, st0, st1, st2, nullptr, tbl3,
      (const float*)d_in[22], (const float*)d_in[23],
      (const float*)d_in[24], (const float*)d_in[25],
      (const float*)d_in[26], (const float*)d_in[27],
      (const float*)d_in[28], (const float*)d_in[29],
      out);
}

// Round 7
// 431.360 us; speedup vs baseline: 6.3852x; 1.0254x over previous
//
#include <hip/hip_runtime.h>
#include <hip/hip_fp16.h>

namespace {

constexpr int BATCH = 8;
constexpr int SLEN  = 262144;
constexpr int TT    = 1023;   // (262144-512)/256 + 1
constexpr int NF    = 257;    // rfft bins
constexpr int NCH   = 24;     // channels stored in H
constexpr int NBT   = BATCH * TT;   // 8184
constexpr int FRS   = NCH * NF;     // frame stride in halfs (6168)
constexpr float EPS = 1e-5f;

typedef _Float16 h2v __attribute__((ext_vector_type(2)));

__device__ inline float fdot2(unsigned a, unsigned b, float c) {
#if __has_builtin(__builtin_amdgcn_fdot2)
  return __builtin_amdgcn_fdot2(__builtin_bit_cast(h2v, a),
                                __builtin_bit_cast(h2v, b), c, false);
#else
  h2v av = __builtin_bit_cast(h2v, a), bv = __builtin_bit_cast(h2v, b);
  return fmaf((float)av[0], (float)bv[0], fmaf((float)av[1], (float)bv[1], c));
#endif
}
__device__ inline unsigned packh2(float a, float b) {
  h2v v; v[0] = (_Float16)a; v[1] = (_Float16)b;
  return __builtin_bit_cast(unsigned, v);
}
__device__ inline unsigned short f2h(float v) {
  return __builtin_bit_cast(unsigned short, (_Float16)v);
}
__device__ inline int div257(int e) { return (e * 65282) >> 24; }  // valid e<6168

// ---------------------------------------------------------------------------
// Kernel A: STFT (hann, 512-pt rfft) + l0 TD block. One workgroup per (b,t).
// DFT: bin-pair (k,256-k) split across lane k (even-n chains) and lane k+128
// (odd-n chains), 32 iters each, combined via LDS. All 256 lanes active.
// ---------------------------------------------------------------------------
__global__ __launch_bounds__(256, 8) void stft_l0_kernel(
    const float* __restrict__ x,
    const float* __restrict__ W1g, const float* __restrict__ b1g,
    const float* __restrict__ W2g, const float* __restrict__ b2g,
    __half* __restrict__ H, float* __restrict__ stats0)
{
  __shared__ float  xw[512];     // windowed frame
  __shared__ __align__(16) float2 abE[128];  // ab[2j]   (even n)
  __shared__ __align__(16) float2 abO[128];  // ab[2j+1] (odd n)
  __shared__ float2 oxc[128];    // odd-lane partial sums exchange
  __shared__ float  sre[NF + 2];
  __shared__ float  sim[NF + 2];
  __shared__ float  h1[4][NF + 2];
  __shared__ float  wW1[24], wb1[4], wW2[96], wb2[8];
  __shared__ float  red[8];

  const int tid = threadIdx.x;
  const int bt  = blockIdx.x;
  const int b   = bt / TT;
  const int t   = bt - b * TT;
  const float* xp = x + (size_t)b * SLEN + (size_t)t * 256;

  if (tid < 24) wW1[tid] = W1g[tid];
  if (tid < 4)  wb1[tid] = b1g[tid];
  if (tid < 96) wW2[tid] = W2g[tid];
  if (tid < 8)  wb2[tid] = b2g[tid];

  const float STEP = 6.283185307179586f / 512.0f;
  for (int n = tid; n < 512; n += 256) {
    float sv, cv;
    sincosf(STEP * (float)n, &sv, &cv);
    xw[n] = xp[n] * (0.5f - 0.5f * cv);   // hann window
  }
  __syncthreads();

  if (tid < 128) {      // abE[j] = ab[2j]; ab[0] = 0
    const int n = 2 * tid;
    abE[tid] = (n == 0) ? make_float2(0.f, 0.f)
                        : make_float2(xw[n] + xw[512 - n], xw[n] - xw[512 - n]);
  } else {              // abO[j] = ab[2j+1]
    const int n = 2 * (tid - 128) + 1;
    abO[tid - 128] = make_float2(xw[n] + xw[512 - n], xw[n] - xw[512 - n]);
  }
  __syncthreads();

  const float x0 = xw[0], x256 = xw[256];
  {
    const int  k = tid & 127;
    const bool P = (tid >= 128);              // parity: odd-n chains
    float s1, c1;
    sincosf(STEP * (float)k, &s1, &c1);
    const float c2 = fmaf(c1,c1,-s1*s1), s2 = 2.f*c1*s1;
    const float c3 = fmaf(c2,c1,-s2*s1), s3 = fmaf(c2,s1, s2*c1);
    const float c4 = fmaf(c2,c2,-s2*s2), s4 = 2.f*c2*s2;
    const float c5 = fmaf(c4,c1,-s4*s1), s5 = fmaf(c4,s1, s4*c1);
    const float c6 = fmaf(c4,c2,-s4*s2), s6 = fmaf(c4,s2, s4*c2);
    const float c7 = fmaf(c4,c3,-s4*s3), s7 = fmaf(c4,s3, s4*c3);
    const float c8 = fmaf(c4,c4,-s4*s4), s8 = 2.f*c4*s4;
    float cA = P ? c1 : 1.f, sA = P ? s1 : 0.f;   // n0 = P
    float cB = P ? c3 : c2,  sB = P ? s3 : s2;    // n0 = P+2
    float cC = P ? c5 : c4,  sC = P ? s5 : s4;    // n0 = P+4
    float cD = P ? c7 : c6,  sD = P ? s7 : s6;    // n0 = P+6
    const float4* ab4 = P ? (const float4*)abO : (const float4*)abE;
    float re = 0.f, im = 0.f;
    for (int m = 0; m < 32; ++m) {
      const float4 q0 = ab4[2*m];       // entries 4m, 4m+1 (n = 8m+P, 8m+2+P)
      const float4 q1 = ab4[2*m + 1];   // entries 4m+2, 4m+3
      re = fmaf(q0.x, cA, re); im = fmaf(q0.y, sA, im);
      re = fmaf(q0.z, cB, re); im = fmaf(q0.w, sB, im);
      re = fmaf(q1.x, cC, re); im = fmaf(q1.y, sC, im);
      re = fmaf(q1.z, cD, re); im = fmaf(q1.w, sD, im);
      float t0;
      t0 = fmaf(cA, c8, -sA*s8); sA = fmaf(cA, s8, sA*c8); cA = t0;
      t0 = fmaf(cB, c8, -sB*s8); sB = fmaf(cB, s8, sB*c8); cB = t0;
      t0 = fmaf(cC, c8, -sC*s8); sC = fmaf(cC, s8, sC*c8); cC = t0;
      t0 = fmaf(cD, c8, -sD*s8); sD = fmaf(cD, s8, sD*c8); cD = t0;
    }
    if (P) oxc[k] = make_float2(re, im);

    // bin 128 contribution: lane tid handles n = tid
    float tr = 0.f, ti = 0.f;
    if (tid & 1) {   // odd n: im term = -(-1)^((n-1)/2) * ab[n].y
      const float v = abO[tid >> 1].y;
      ti = ((tid >> 1) & 1) ? v : -v;
    } else {         // even n: re term = (-1)^(n/2) * ab[n].x
      const float v = abE[tid >> 1].x;
      tr = ((tid >> 1) & 1) ? -v : v;
    }
    #pragma unroll
    for (int off = 32; off > 0; off >>= 1) {
      tr += __shfl_down(tr, off, 64);
      ti += __shfl_down(ti, off, 64);
    }
    if ((tid & 63) == 0) { red[(tid >> 6)*2] = tr; red[(tid >> 6)*2 + 1] = ti; }
    __syncthreads();

    if (!P) {
      const float rb  = x0 + ((k & 1) ? -x256 : x256);
      const float reo = oxc[k].x, imo = oxc[k].y;
      sre[1 + k]       = rb + re + reo;
      sim[1 + k]       = -(im + imo);
      sre[1 + 256 - k] = rb + re - reo;
      sim[1 + 256 - k] = im - imo;
    }
    if (tid == 0) {
      sre[1 + 128] = x0 + x256 + red[0] + red[2] + red[4] + red[6];
      sim[1 + 128] = red[1] + red[3] + red[5] + red[7];
      sre[0] = 0.f; sim[0] = 0.f; sre[258] = 0.f; sim[258] = 0.f;
    }
  }
  __syncthreads();

  // conv1: (f,2) -> (f,4), k=3 same, relu
  for (int f = tid; f < NF; f += 256) {
    float acc[4] = {wb1[0], wb1[1], wb1[2], wb1[3]};
    #pragma unroll
    for (int i = 0; i < 3; ++i) {
      float vr = sre[f + i], vi = sim[f + i];
      #pragma unroll
      for (int c = 0; c < 4; ++c)
        acc[c] = fmaf(vr, wW1[(i*2+0)*4 + c], fmaf(vi, wW1[(i*2+1)*4 + c], acc[c]));
    }
    #pragma unroll
    for (int c = 0; c < 4; ++c) h1[c][f + 1] = fmaxf(acc[c], 0.f);
  }
  if (tid < 4) { h1[tid][0] = 0.f; h1[tid][NF + 1] = 0.f; }
  __syncthreads();

  // conv2: (f,4) -> (f,8), relu, store fp16 channel-major + stats (rounded)
  const size_t obase = (size_t)bt * FRS;
  float ps1 = 0.f, ps2 = 0.f;
  for (int f = tid; f < NF; f += 256) {
    float acc[8];
    #pragma unroll
    for (int c = 0; c < 8; ++c) acc[c] = wb2[c];
    #pragma unroll
    for (int i = 0; i < 3; ++i)
      #pragma unroll
      for (int c4 = 0; c4 < 4; ++c4) {
        float hv = h1[c4][f + i];
        #pragma unroll
        for (int c = 0; c < 8; ++c)
          acc[c] = fmaf(hv, wW2[(i*4+c4)*8 + c], acc[c]);
      }
    #pragma unroll
    for (int c = 0; c < 8; ++c) {
      const __half hv = __float2half(fmaxf(acc[c], 0.f));
      H[obase + (size_t)c * NF + f] = hv;
      const float v = __half2float(hv);
      ps1 += v;
      ps2 = fmaf(v, v, ps2);
    }
  }
  #pragma unroll
  for (int off = 32; off > 0; off >>= 1) {
    ps1 += __shfl_down(ps1, off, 64);
    ps2 += __shfl_down(ps2, off, 64);
  }
  __syncthreads();  // red[] reused
  if ((tid & 63) == 0) { red[(tid >> 6) * 2] = ps1; red[(tid >> 6) * 2 + 1] = ps2; }
  __syncthreads();
  if (tid == 0) {
    stats0[bt * 2]     = red[0] + red[2] + red[4] + red[6];
    stats0[bt * 2 + 1] = red[1] + red[3] + red[5] + red[7];
  }
}

// ---------------------------------------------------------------------------
// Fold all three LN/depthwise tables -> fp16 planes, channel-major [c][f]:
//   plane 0..2: P_dt = g*dw_dt; plane 3..5: Q0/Q1/Q2 causal-boundary biases.
// ---------------------------------------------------------------------------
__device__ inline void fold_one(int idx, int CIN,
    const float* g, const float* bn, const float* dw, __half* dst, int NEL) {
  const int c = div257(idx), f = idx - c * 257;
  const int s = f * CIN + c;
  const float gv = g[s], bv = bn[s];
  const float d0 = dw[s*3], d1 = dw[s*3+1], d2 = dw[s*3+2];
  dst[idx]         = __float2half(gv * d0);
  dst[NEL + idx]   = __float2half(gv * d1);
  dst[2*NEL + idx] = __float2half(gv * d2);
  dst[3*NEL + idx] = __float2half(bv * (d0 + d1 + d2));
  dst[4*NEL + idx] = __float2half(bv * (d1 + d2));
  dst[5*NEL + idx] = __float2half(bv * d2);
}

__global__ __launch_bounds__(256) void fold_all(
    const float* g1, const float* bn1, const float* dw1, __half* t1,
    const float* g2, const float* bn2, const float* dw2, __half* t2,
    const float* g3, const float* bn3, const float* dw3, __half* t3)
{
  int idx = blockIdx.x * 256 + threadIdx.x;
  if (idx < 8*257) { fold_one(idx, 8, g1, bn1, dw1, t1, 8*257); return; }
  idx -= 8*257;
  if (idx < 16*257) { fold_one(idx, 16, g2, bn2, dw2, t2, 16*257); return; }
  idx -= 16*257;
  if (idx < 24*257) fold_one(idx, 24, g3, bn3, dw3, t3, 24*257);
}

// ---------------------------------------------------------------------------
// Layer kernel, one block per (b,t). Transposed LDS (y_t[f][c], h1_t[f][c])
// + packed-half2 dot2 contraction for conv1/conv2/fc1.
// ---------------------------------------------------------------------------
template<int CIN, bool HEAD>
__global__ __launch_bounds__(256, 8) void layer_bt(
    const __half* __restrict__ H, __half* __restrict__ Hout,
    const float* __restrict__ st0, const float* __restrict__ st1,
    const float* __restrict__ st2, float* __restrict__ stats_out,
    const __half* __restrict__ tbl,
    const float* __restrict__ W1g, const float* __restrict__ b1g,
    const float* __restrict__ W2g, const float* __restrict__ b2g,
    const float* __restrict__ fc1W, const float* __restrict__ fc1b,
    const float* __restrict__ fc2W, const float* __restrict__ fc2b,
    float* __restrict__ out)
{
  constexpr int NEL   = CIN * NF;               // 2056 / 4112 / 6168
  constexpr int NP2   = NEL / 2;
  constexpr int NPER2 = (NP2 + 255) / 256;      // 5 / 9 / 13
  constexpr int TAIL2 = NP2 - 256 * (NPER2 - 1);
  constexpr int PC1   = CIN + 2;                // 10 / 18 / 26 halfs (odd banks)
  constexpr int PC2   = 10;                     // h1 row: 8 + 2 pad
  constexpr int NQ1   = CIN / 2;                // channel pairs

  __shared__ unsigned short y_t[259 * PC1];     // [row f+1][c]; reused as out2_t
  __shared__ unsigned short h1_t[259 * PC2];    // [row f+1][c8]
  __shared__ unsigned w1p[3 * NQ1 * 8];         // half2-packed conv1 weights
  __shared__ unsigned w2p[96];                  // half2-packed conv2 weights
  __shared__ float wb1[8], wb2[8];
  __shared__ float red[8];
  __shared__ unsigned wfc1p[HEAD ? 48 : 1];     // half2-packed fc1 weights

  const int tid = threadIdx.x;
  const int bt  = blockIdx.x;
  const int b   = bt / TT;
  const int t   = bt - b * TT;

  // ---- weight packing + halo init ----
  for (int idx = tid; idx < 3 * NQ1 * 8; idx += 256) {
    const int o = idx & 7, q = (idx >> 3) % NQ1, i = idx / (NQ1 * 8);
    w1p[idx] = packh2(W1g[(i*CIN + 2*q)*8 + o], W1g[(i*CIN + 2*q + 1)*8 + o]);
  }
  if (tid < 96) {
    const int o = tid & 7, q = (tid >> 3) & 3, i = tid >> 5;
    w2p[tid] = packh2(W2g[(i*8 + 2*q)*8 + o], W2g[(i*8 + 2*q + 1)*8 + o]);
  }
  if (tid < 8) { wb1[tid] = b1g[tid]; wb2[tid] = b2g[tid]; }
  if (tid < PC1) { y_t[tid] = 0; y_t[258*PC1 + tid] = 0; }
  if (tid < PC2) { h1_t[tid] = 0; h1_t[258*PC2 + tid] = 0; }
  if constexpr (HEAD) {
    if (tid < 48) {
      const int q = tid & 15, i = tid >> 4;
      wfc1p[tid] = packh2(fc1W[i*32 + 2*q], fc1W[i*32 + 2*q + 1]);
    }
  }

  // ---- per-frame LN stats from producer partials ----
  float mu0 = 0.f, rs0 = 0.f, mu1 = 0.f, rs1 = 0.f, mu2, rs2;
  {
    const float inv = 1.0f / (float)NEL;
    float s1 = st0[bt*2], s2v = st0[bt*2+1];
    if constexpr (CIN >= 16) { s1 += st1[bt*2]; s2v += st1[bt*2+1]; }
    if constexpr (CIN >= 24) { s1 += st2[bt*2]; s2v += st2[bt*2+1]; }
    mu2 = s1 * inv; rs2 = rsqrtf(s2v * inv - mu2*mu2 + EPS);
    if (t >= 1) {
      const int fb = bt - 1;
      float a = st0[fb*2], c = st0[fb*2+1];
      if constexpr (CIN >= 16) { a += st1[fb*2]; c += st1[fb*2+1]; }
      if constexpr (CIN >= 24) { a += st2[fb*2]; c += st2[fb*2+1]; }
      mu1 = a * inv; rs1 = rsqrtf(c * inv - mu1*mu1 + EPS);
    }
    if (t >= 2) {
      const int fb = bt - 2;
      float a = st0[fb*2], c = st0[fb*2+1];
      if constexpr (CIN >= 16) { a += st1[fb*2]; c += st1[fb*2+1]; }
      if constexpr (CIN >= 24) { a += st2[fb*2]; c += st2[fb*2+1]; }
      mu0 = a * inv; rs0 = rsqrtf(c * inv - mu0*mu0 + EPS);
    }
  }

  const int base = b * TT;
  const __half2* f2p = (const __half2*)(H + (size_t)bt * FRS);
  const __half2* f1p = (const __half2*)(H + (size_t)max(bt - 1, base) * FRS);
  const __half2* f0p = (const __half2*)(H + (size_t)max(bt - 2, base) * FRS);
  const __half2* P0p = (const __half2*)tbl;
  const __half2* P1p = (const __half2*)(tbl + NEL);
  const __half2* P2p = (const __half2*)(tbl + 2 * NEL);
  const int qsel = (t >= 2) ? 0 : (t == 1 ? 1 : 2);
  const __half2* Qp  = (const __half2*)(tbl + (3 + qsel) * NEL);

  // ---- stage A: LN + causal depthwise -> y_t (transposed) ----
  #pragma unroll
  for (int j = 0; j < NPER2; ++j) {
    const bool act = (j < NPER2 - 1) || (tid < TAIL2);
    if (act) {
      const int p  = tid + 256 * j;
      const int e0 = 2 * p;
      const int c0 = div257(e0);
      const int fi = e0 - c0 * 257;
      const float2 xa = __half22float2(f0p[p]);
      const float2 xb = __half22float2(f1p[p]);
      const float2 xc = __half22float2(f2p[p]);
      const float2 pa = __half22float2(P0p[p]);
      const float2 pb = __half22float2(P1p[p]);
      const float2 pc = __half22float2(P2p[p]);
      const float2 qq = __half22float2(Qp[p]);
      const float y0 = fmaf((xa.x - mu0) * rs0, pa.x,
                       fmaf((xb.x - mu1) * rs1, pb.x,
                       fmaf((xc.x - mu2) * rs2, pc.x, qq.x)));
      const float y1 = fmaf((xa.y - mu0) * rs0, pa.y,
                       fmaf((xb.y - mu1) * rs1, pb.y,
                       fmaf((xc.y - mu2) * rs2, pc.y, qq.y)));
      const int a1 = (fi + 1) * PC1 + c0;
      y_t[a1] = f2h(y0);
      const int a2 = (fi == 256) ? (PC1 + c0 + 1) : (a1 + PC1);
      y_t[a2] = f2h(y1);
    }
  }
  __syncthreads();

  // ---- stage B: conv1 (f,CIN)->(f,8) via dot2, relu ----
  {
    const int f = tid;  // output f = 0..255; reads y_t rows f..f+2
    float acc[8];
    #pragma unroll
    for (int c = 0; c < 8; ++c) acc[c] = wb1[c];
    const unsigned* yw = (const unsigned*)y_t;
    #pragma unroll
    for (int i = 0; i < 3; ++i) {
      const unsigned* row = yw + (f + i) * (PC1 / 2);
      for (int q = 0; q < NQ1; ++q) {
        const unsigned yv = row[q];
        #pragma unroll
        for (int c = 0; c < 8; ++c)
          acc[c] = fdot2(yv, w1p[(i * NQ1 + q) * 8 + c], acc[c]);
      }
    }
    unsigned* hw = (unsigned*)h1_t + (f + 1) * (PC2 / 2);
    #pragma unroll
    for (int k = 0; k < 4; ++k)
      hw[k] = packh2(fmaxf(acc[2*k], 0.f), fmaxf(acc[2*k+1], 0.f));
  }
  if (tid < 8) {  // sidecar: f=256 (row 257), out-channel = tid
    float a = wb1[tid];
    const unsigned* yw = (const unsigned*)y_t;
    #pragma unroll
    for (int i = 0; i < 3; ++i) {
      const unsigned* row = yw + (256 + i) * (PC1 / 2);
      for (int q = 0; q < NQ1; ++q)
        a = fdot2(row[q], w1p[(i * NQ1 + q) * 8 + tid], a);
    }
    h1_t[257 * PC2 + tid] = f2h(fmaxf(a, 0.f));
  }
  __syncthreads();

  // ---- stage C: conv2 (f,8)->(f,8) via dot2, relu ----
  float ps1 = 0.f, ps2 = 0.f;
  {
    const int f = tid;
    float o2[8];
    #pragma unroll
    for (int c = 0; c < 8; ++c) o2[c] = wb2[c];
    const unsigned* hw = (const unsigned*)h1_t;
    #pragma unroll
    for (int i = 0; i < 3; ++i) {
      const unsigned* row = hw + (f + i) * (PC2 / 2);
      #pragma unroll
      for (int q = 0; q < 4; ++q) {
        const unsigned hv = row[q];
        #pragma unroll
        for (int c = 0; c < 8; ++c)
          o2[c] = fdot2(hv, w2p[(i*4 + q)*8 + c], o2[c]);
      }
    }
    if constexpr (!HEAD) {
      const size_t ob = (size_t)bt * FRS + (size_t)CIN * NF;
      #pragma unroll
      for (int c = 0; c < 8; ++c) {
        const __half hv = __float2half(fmaxf(o2[c], 0.f));
        Hout[ob + (size_t)c * NF + f] = hv;
        const float v = __half2float(hv);
        ps1 += v;
        ps2 = fmaf(v, v, ps2);
      }
    } else {
      unsigned* ow = (unsigned*)y_t + f * (PC1 / 2);  // out2_t row f (y_t dead)
      #pragma unroll
      for (int k = 0; k < 4; ++k)
        ow[k] = packh2(fmaxf(o2[2*k], 0.f), fmaxf(o2[2*k+1], 0.f));
    }
  }
  if (tid >= 8 && tid < 16) {  // sidecar: f=256, ch = tid-8
    const int c8 = tid - 8;
    float a = wb2[c8];
    const unsigned* hw = (const unsigned*)h1_t;
    #pragma unroll
    for (int i = 0; i < 3; ++i) {
      const unsigned* row = hw + (256 + i) * (PC2 / 2);
      #pragma unroll
      for (int q = 0; q < 4; ++q)
        a = fdot2(row[q], w2p[(i*4 + q)*8 + c8], a);
    }
    if constexpr (!HEAD) {
      const size_t ob = (size_t)bt * FRS + (size_t)CIN * NF;
      const __half hv = __float2half(fmaxf(a, 0.f));
      Hout[ob + (size_t)c8 * NF + 256] = hv;
      const float v = __half2float(hv);
      ps1 += v;
      ps2 = fmaf(v, v, ps2);
    } else {
      y_t[256 * PC1 + c8] = f2h(fmaxf(a, 0.f));
    }
  }

  if constexpr (!HEAD) {
    #pragma unroll
    for (int off = 32; off > 0; off >>= 1) {
      ps1 += __shfl_down(ps1, off, 64);
      ps2 += __shfl_down(ps2, off, 64);
    }
    if ((tid & 63) == 0) { red[(tid >> 6)*2] = ps1; red[(tid >> 6)*2+1] = ps2; }
    __syncthreads();
    if (tid == 0) {
      stats_out[bt*2]     = red[0] + red[2] + red[4] + red[6];
      stats_out[bt*2 + 1] = red[1] + red[3] + red[5] + red[7];
    }
  } else {
    __syncthreads();  // out2_t complete
    // ---- stage D: fc1 (valid k=3, 32ch) + relu + fc2 + sigmoid ----
    float part = 0.f;
    if (tid < NF - 2) {
      const unsigned short* xgu = (const unsigned short*)f2p;  // frame t, L1-warm
      float acc = fc1b[0];
      #pragma unroll
      for (int i = 0; i < 3; ++i) {
        const int pos = tid + i;
        for (int q = 0; q < 12; ++q) {   // raw-input channel pairs
          const unsigned lo = xgu[(2*q) * 257 + pos];
          const unsigned hi = xgu[(2*q + 1) * 257 + pos];
          acc = fdot2(lo | (hi << 16), wfc1p[i*16 + q], acc);
        }
        const unsigned* orow = (const unsigned*)y_t + pos * (PC1 / 2);
        #pragma unroll
        for (int q = 0; q < 4; ++q)      // this layer's 8 output channels
          acc = fdot2(orow[q], wfc1p[i*16 + 12 + q], acc);
      }
      part = fmaxf(acc, 0.f) * fc2W[tid];
    }
    #pragma unroll
    for (int off = 32; off > 0; off >>= 1) part += __shfl_down(part, off, 64);
    if ((tid & 63) == 0) red[tid >> 6] = part;
    __syncthreads();
    if (tid == 0) {
      const float tot = red[0] + red[1] + red[2] + red[3] + fc2b[0];
      out[bt] = 1.0f / (1.0f + expf(-tot));
    }
  }
}

}  // namespace

extern "C" void kernel_launch(void* const* d_in, const int* in_sizes, int n_in,
                              void* d_out, int out_size, void* d_ws, size_t ws_size,
                              hipStream_t stream) {
  (void)in_sizes; (void)n_in; (void)out_size; (void)ws_size;
  const float* x = (const float*)d_in[0];
  float* out = (float*)d_out;
  char*  wsb = (char*)d_ws;

  __half* H   = (__half*)wsb;                       // NBT*FRS halfs = ~101 MB
  char* p = wsb + (size_t)NBT * FRS * sizeof(__half);
  float* st0  = (float*)p; p += 2 * NBT * sizeof(float);
  float* st1  = (float*)p; p += 2 * NBT * sizeof(float);
  float* st2  = (float*)p; p += 2 * NBT * sizeof(float);
  __half* tbl1 = (__half*)p; p += 6 * (8  * NF) * sizeof(__half);
  __half* tbl2 = (__half*)p; p += 6 * (16 * NF) * sizeof(__half);
  __half* tbl3 = (__half*)p;

  dim3 blk(256);

  fold_all<<<dim3((48 * 257 + 255) / 256), blk, 0, stream>>>(
      (const float*)d_in[5],  (const float*)d_in[6],  (const float*)d_in[7],  tbl1,
      (const float*)d_in[12], (const float*)d_in[13], (const float*)d_in[14], tbl2,
      (const float*)d_in[19], (const float*)d_in[20], (const float*)d_in[21], tbl3);

  stft_l0_kernel<<<dim3(NBT), blk, 0, stream>>>(
      x, (const float*)d_in[1], (const float*)d_in[2],
      (const float*)d_in[3], (const float*)d_in[4], H, st0);

  layer_bt<8, false><<<dim3(NBT), blk, 0, stream>>>(
      H, H, st0, nullptr, nullptr, st1, tbl1,
      (const float*)d_in[8], (const float*)d_in[9],
      (const float*)d_in[10], (const float*)d_in[11],
      nullptr, nullptr, nullptr, nullptr, nullptr);

  layer_bt<16, false><<<dim3(NBT), blk, 0, stream>>>(
      H, H, st0, st1, nullptr, st2, tbl2,
      (const float*)d_in[15], (const float*)d_in[16],
      (const float*)d_in[17], (const float*)d_in[18],
      nullptr, nullptr, nullptr, nullptr, nullptr);

  layer_bt<24, true><<<dim3(NBT), blk, 0, stream>>>(
      H, nullptr, st0, st1, st2, nullptr, tbl3,
      (const float*)d_in[22], (const float*)d_in[23],
      (const float*)d_in[24], (const float*)d_in[25],
      (const float*)d_in[26], (const float*)d_in[27],
      (const float*)d_in[28], (const float*)d_in[29],
      out);
}